// Round 1
// baseline (463.579 us; speedup 1.0000x reference)
//
#include <hip/hip_runtime.h>
#include <hip/hip_bf16.h>

typedef __hip_bfloat16 bf16;
typedef __attribute__((ext_vector_type(8))) short short8;
typedef __attribute__((ext_vector_type(4))) short short4v;
typedef __attribute__((ext_vector_type(4))) float f32x4;

#define NB 16
#define NT 1024
#define ND 500
#define NDP 512               /* padded K/N for MFMA */
#define NTOK (NB * NT)
#define TSP 32                /* t split for pool/c kernels */
#define LSTR 32               /* LDS row stride in shorts */
#define INV_SCALE 0.04472135954999579f   /* 1/sqrt(500) */

__device__ __forceinline__ float b2f(bf16 x) { return __bfloat162float(x); }

__device__ __forceinline__ void gload_lds16(const bf16* g, short* l) {
    __builtin_amdgcn_global_load_lds((const __attribute__((address_space(1))) void*)g,
                                     (__attribute__((address_space(3))) void*)l, 16, 0, 0);
}

/* bijective XCD-aware swizzle of the linearized block id (nwg % 8 == 0 for all grids) */
__device__ __forceinline__ void xcd_swizzle(int& bx, int& by, int& bz) {
    int gx = gridDim.x, gy = gridDim.y;
    int nwg = gx * gy * (int)gridDim.z;
    int lin = blockIdx.x + gx * (blockIdx.y + gy * blockIdx.z);
    int cpx = nwg >> 3;
    int swz = (lin & 7) * cpx + (lin >> 3);
    bx = swz % gx;
    int r = swz / gx;
    by = r % gy;
    bz = r / gy;
}

/* =====================================================================
 * MFMA core: 128x128 tile, 4 waves (2x2), each wave 4x4 of 16x16x32.
 * 2-phase double-buffered pipeline: stage(next) overlaps MFMA(cur);
 * single vmcnt(0)+s_barrier per K-step (no full __syncthreads drain).
 * LDS: 2 buffers x (A 4096 + B 4096 shorts) = 16384 shorts = 32 KB.
 * ===================================================================== */
__device__ __forceinline__ void mfma_core(const bf16* __restrict__ Ab, int lda,
                                          const bf16* __restrict__ Bb, int ldb,
                                          int nsteps, short* As, short* Bs,
                                          f32x4 (&acc)[4][4]) {
    const int tid = threadIdx.x;
    const int lane = tid & 63;
    const int wave = tid >> 6;
    const int wy = wave >> 1, wx = wave & 1;
    const int m16 = lane & 15, quad = lane >> 4;
    const int srow = wave * 16 + (lane >> 2);
    const int sseg = lane & 3;
    const bf16* a0 = Ab + (size_t)srow * lda + sseg * 8;
    const bf16* a1 = a0 + (size_t)64 * lda;
    const bf16* b0 = Bb + (size_t)srow * ldb + sseg * 8;
    const bf16* b1 = b0 + (size_t)64 * ldb;
    short* aL0 = As + wave * 512;          /* wave-uniform LDS dests */
    short* aL1 = As + 2048 + wave * 512;
    short* bL0 = Bs + wave * 512;
    short* bL1 = Bs + 2048 + wave * 512;
    /* prologue: stage tile 0 into buffer 0 */
    gload_lds16(a0, aL0);
    gload_lds16(a1, aL1);
    gload_lds16(b0, bL0);
    gload_lds16(b1, bL1);
    asm volatile("s_waitcnt vmcnt(0)" ::: "memory");
    __builtin_amdgcn_s_barrier();
    for (int ks = 0; ks < nsteps; ks++) {
        const int cur = (ks & 1) * 8192;   /* buffer offset in shorts */
        const int nxt = 8192 - cur;
        if (ks + 1 < nsteps) {             /* prefetch next tile into other buffer */
            const int ko = (ks + 1) * 32;
            gload_lds16(a0 + ko, aL0 + nxt);
            gload_lds16(a1 + ko, aL1 + nxt);
            gload_lds16(b0 + ko, bL0 + nxt);
            gload_lds16(b1 + ko, bL1 + nxt);
        }
        short8 af[4], bfv[4];
        #pragma unroll
        for (int i = 0; i < 4; i++)
            af[i] = *(const short8*)&As[cur + (wy * 64 + i * 16 + m16) * LSTR + quad * 8];
        #pragma unroll
        for (int j = 0; j < 4; j++)
            bfv[j] = *(const short8*)&Bs[cur + (wx * 64 + j * 16 + m16) * LSTR + quad * 8];
        #pragma unroll
        for (int i = 0; i < 4; i++)
            #pragma unroll
            for (int j = 0; j < 4; j++)
                acc[i][j] = __builtin_amdgcn_mfma_f32_16x16x32_bf16(af[i], bfv[j], acc[i][j], 0, 0, 0);
        /* drain own prefetch, then align waves: buffer read this iter is safe to
           overwrite next iter, and next buffer is fully visible to all waves. */
        asm volatile("s_waitcnt vmcnt(0)" ::: "memory");
        __builtin_amdgcn_s_barrier();
    }
}

/* ---- W (500x500 fp32 [k][n]) -> Wt (512x512 bf16 [n][k]) ---- */
__global__ void transpose_w3(const float* __restrict__ WK, const float* __restrict__ WQ,
                             const float* __restrict__ WV, bf16* __restrict__ Wt_all) {
    const float* W = (blockIdx.z == 0) ? WK : (blockIdx.z == 1) ? WQ : WV;
    bf16* Wt = Wt_all + (size_t)blockIdx.z * NDP * NDP;
    __shared__ float t[32][33];
    int n0 = blockIdx.x * 32, k0 = blockIdx.y * 32;
    int a = threadIdx.x & 31, bq = threadIdx.x >> 5;
    #pragma unroll
    for (int it = 0; it < 4; it++) {
        int k = k0 + bq + it * 8, n = n0 + a;
        t[bq + it * 8][a] = (k < ND && n < ND) ? W[k * ND + n] : 0.f;
    }
    __syncthreads();
    #pragma unroll
    for (int it = 0; it < 4; it++) {
        int n = n0 + bq + it * 8;
        Wt[(size_t)n * NDP + k0 + a] = __float2bfloat16(t[a][bq + it * 8]);
    }
}

/* ---- build g (B,T,512) bf16 ---- */
__global__ void build_g(const int* __restrict__ words, const int* __restrict__ pos,
                        const int* __restrict__ ner, const int* __restrict__ chunks,
                        const int* __restrict__ subj_pos, const int* __restrict__ obj_pos,
                        const int* __restrict__ on_path, const float* __restrict__ dep_feat,
                        const float* __restrict__ emb_w, const float* __restrict__ pos_w,
                        const float* __restrict__ ner_w, const float* __restrict__ chunk_w,
                        const float* __restrict__ position_w, bf16* __restrict__ g) {
    int tok = blockIdx.x;
    int w = words[tok], p = pos[tok], n = ner[tok], ck = chunks[tok];
    int sp = subj_pos[tok], op = obj_pos[tok], onp = on_path[tok];
    bf16* gr = g + (size_t)tok * NDP;
    for (int d = threadIdx.x; d < NDP; d += blockDim.x) {
        float v;
        if      (d < 300) v = emb_w[(size_t)w * 300 + d];
        else if (d < 335) v = pos_w[p * 35 + (d - 300)];
        else if (d < 365) v = ner_w[n * 30 + (d - 335)];
        else if (d < 395) v = chunk_w[ck * 30 + (d - 365)];
        else if (d < 425) v = position_w[sp * 30 + (d - 395)];
        else if (d < 455) v = position_w[op * 30 + (d - 425)];
        else if (d == 455) v = (float)onp;
        else if (d < 500) v = dep_feat[(size_t)tok * 44 + (d - 456)];
        else              v = 0.f;
        gr[d] = __float2bfloat16(v);
    }
}

/* ---- subj max pool partials ---- */
__global__ void pool_part(const bf16* __restrict__ g, const int* __restrict__ subj_pos,
                          float* __restrict__ part) {
    int b = blockIdx.x, s = blockIdx.y;
    int c0 = threadIdx.x * 8;
    const bf16* gb = g + (size_t)b * NT * NDP + c0;
    const int* sp = subj_pos + b * NT;
    float mx[8];
    #pragma unroll
    for (int i = 0; i < 8; i++) mx[i] = -INFINITY;
    int t0 = s * (NT / TSP), t1 = t0 + (NT / TSP);
    for (int t = t0; t < t1; t++) {
        int masked = (sp[t] != 0);
        short8 v8 = *(const short8*)(gb + (size_t)t * NDP);
        #pragma unroll
        for (int i = 0; i < 8; i++) {
            float v = masked ? -1e12f : b2f(((bf16*)&v8)[i]);
            mx[i] = fmaxf(mx[i], v);
        }
    }
    float* pr = part + ((size_t)(b * TSP + s)) * NDP + c0;
    #pragma unroll
    for (int i = 0; i < 8; i++) pr[i] = mx[i];
}

/* ---- fused: pool reduce -> subj; q = relu(subj@(Wq0+Wq1)+bq); w2 = relu(q@Wc0+bc)*Wk ---- */
__global__ __launch_bounds__(512) void fused_qw2(const float* __restrict__ part,
                                                 const float* __restrict__ Wq_w, const float* __restrict__ Wq_b,
                                                 const float* __restrict__ Wc_w, const float* __restrict__ Wc_b,
                                                 const float* __restrict__ Wk_w,
                                                 float* __restrict__ subj, float* __restrict__ w2) {
    int b = blockIdx.x, d = threadIdx.x;
    __shared__ float xs[512];
    float mx = -INFINITY;
    #pragma unroll
    for (int s = 0; s < TSP; s++) mx = fmaxf(mx, part[((size_t)(b * TSP + s)) * NDP + d]);
    xs[d] = mx;
    if (d < ND) subj[b * ND + d] = mx;
    __syncthreads();
    float q = 0.f;
    if (d < ND) {
        float a0 = 0.f, a1 = 0.f, a2 = 0.f, a3 = 0.f;
        int j = 0;
        for (; j + 4 <= ND; j += 4) {
            a0 += xs[j]     * (Wq_w[(size_t)j * ND + d]           + Wq_w[(size_t)(j + ND) * ND + d]);
            a1 += xs[j + 1] * (Wq_w[(size_t)(j + 1) * ND + d]     + Wq_w[(size_t)(j + 1 + ND) * ND + d]);
            a2 += xs[j + 2] * (Wq_w[(size_t)(j + 2) * ND + d]     + Wq_w[(size_t)(j + 2 + ND) * ND + d]);
            a3 += xs[j + 3] * (Wq_w[(size_t)(j + 3) * ND + d]     + Wq_w[(size_t)(j + 3 + ND) * ND + d]);
        }
        for (; j < ND; j++) a0 += xs[j] * (Wq_w[(size_t)j * ND + d] + Wq_w[(size_t)(j + ND) * ND + d]);
        q = fmaxf(((a0 + a1) + (a2 + a3)) + Wq_b[d], 0.f);
    }
    __syncthreads();
    xs[d] = q;
    __syncthreads();
    if (d < ND) {
        float a0 = 0.f, a1 = 0.f, a2 = 0.f, a3 = 0.f;
        int j = 0;
        for (; j + 4 <= ND; j += 4) {
            a0 += xs[j]     * Wc_w[(size_t)j * ND + d];
            a1 += xs[j + 1] * Wc_w[(size_t)(j + 1) * ND + d];
            a2 += xs[j + 2] * Wc_w[(size_t)(j + 2) * ND + d];
            a3 += xs[j + 3] * Wc_w[(size_t)(j + 3) * ND + d];
        }
        for (; j < ND; j++) a0 += xs[j] * Wc_w[(size_t)j * ND + d];
        w2[b * ND + d] = fmaxf(((a0 + a1) + (a2 + a3)) + Wc_b[d], 0.f) * Wk_w[d];
    }
}

/* ---- klog ---- */
__global__ void compute_klog(const bf16* __restrict__ g, const float* __restrict__ w2,
                             const float* __restrict__ Wk_b, float* __restrict__ klog) {
    int tok = blockIdx.x * 4 + (threadIdx.x >> 6);
    int lane = threadIdx.x & 63;
    int b = tok >> 10;
    const bf16* gr = g + (size_t)tok * NDP + lane * 8;
    const float* wr = w2 + b * ND + lane * 8;
    short8 v8 = *(const short8*)gr;
    float acc = 0.f;
    #pragma unroll
    for (int i = 0; i < 8; i++) acc += b2f(((bf16*)&v8)[i]) * wr[i];
    #pragma unroll
    for (int off = 32; off; off >>= 1) acc += __shfl_down(acc, off, 64);
    if (lane == 0) klog[tok] = acc + Wk_b[0];
}

/* ---- softmax over T ---- */
__global__ void softmax_k(const float* __restrict__ klog, float* __restrict__ k) {
    int b = blockIdx.x, tid = threadIdx.x;
    __shared__ float red[256];
    float m = -INFINITY;
    for (int t = tid; t < NT; t += 256) m = fmaxf(m, klog[b * NT + t]);
    red[tid] = m; __syncthreads();
    for (int s = 128; s; s >>= 1) { if (tid < s) red[tid] = fmaxf(red[tid], red[tid + s]); __syncthreads(); }
    m = red[0]; __syncthreads();
    float sum = 0.f;
    for (int t = tid; t < NT; t += 256) sum += expf(klog[b * NT + t] - m);
    red[tid] = sum; __syncthreads();
    for (int s = 128; s; s >>= 1) { if (tid < s) red[tid] += red[tid + s]; __syncthreads(); }
    float inv = 1.f / red[0];
    for (int t = tid; t < NT; t += 256) k[b * NT + t] = expf(klog[b * NT + t] - m) * inv;
}

/* ---- c = sum_t k*g partials ---- */
__global__ void c_part(const bf16* __restrict__ g, const float* __restrict__ k,
                       float* __restrict__ part) {
    int b = blockIdx.x, s = blockIdx.y;
    int c0 = threadIdx.x * 8;
    const bf16* gb = g + (size_t)b * NT * NDP + c0;
    const float* kb = k + b * NT;
    float acc[8] = {};
    int t0 = s * (NT / TSP), t1 = t0 + (NT / TSP);
    for (int t = t0; t < t1; t++) {
        float kv = kb[t];
        short8 v8 = *(const short8*)(gb + (size_t)t * NDP);
        #pragma unroll
        for (int i = 0; i < 8; i++) acc[i] += kv * b2f(((bf16*)&v8)[i]);
    }
    float* pr = part + ((size_t)(b * TSP + s)) * NDP + c0;
    #pragma unroll
    for (int i = 0; i < 8; i++) pr[i] = acc[i];
}

/* ---- fused: c reduce; m = relu(c@Wm0 + subj@(Wm1+Wm2) + bm) ---- */
__global__ __launch_bounds__(512) void fused_m(const float* __restrict__ part,
                                               const float* __restrict__ subj,
                                               const float* __restrict__ Wm_w, const float* __restrict__ Wm_b,
                                               float* __restrict__ mv) {
    int b = blockIdx.x, d = threadIdx.x;
    __shared__ float cs[512];
    __shared__ float ss[512];
    float a = 0.f;
    #pragma unroll
    for (int s = 0; s < TSP; s++) a += part[((size_t)(b * TSP + s)) * NDP + d];
    cs[d] = a;
    ss[d] = (d < ND) ? subj[b * ND + d] : 0.f;
    __syncthreads();
    if (d < ND) {
        float a0 = 0.f, a1 = 0.f;
        for (int j = 0; j < ND; j++) {
            a0 += cs[j] * Wm_w[(size_t)j * ND + d];
            a1 += ss[j] * (Wm_w[(size_t)(ND + j) * ND + d] + Wm_w[(size_t)(2 * ND + j) * ND + d]);
        }
        mv[b * ND + d] = fmaxf(a0 + a1 + Wm_b[d], 0.f);
    }
}

/* ---- MFMA projections K/Q/V. z==2 (value) writes TRANSPOSED Vt[b][c][s] directly ---- */
__global__ __launch_bounds__(256) void mfma_proj3(const bf16* __restrict__ g, const bf16* __restrict__ Wt_all,
                                                  const float* __restrict__ bK, const float* __restrict__ bQ,
                                                  const float* __restrict__ bV, bf16* __restrict__ kqv,
                                                  bf16* __restrict__ valT) {
    __shared__ short LB[16384];
    short* As = LB;
    short* Bs = LB + 4096;
    f32x4 acc[4][4] = {};
    int bx, by, bz;
    xcd_swizzle(bx, by, bz);
    const int zz = bz;
    const bf16* Wt = Wt_all + (size_t)zz * NDP * NDP;
    const float* bias = (zz == 0) ? bK : (zz == 1) ? bQ : bV;
    bf16* out = kqv + (size_t)zz * NTOK * NDP;
    int row0 = bx * 128, col0 = by * 128;
    mfma_core(g + (size_t)row0 * NDP, NDP, Wt + (size_t)col0 * NDP, NDP, NDP / 32, As, Bs, acc);
    const int tid = threadIdx.x, lane = tid & 63, wave = tid >> 6;
    const int wx = wave & 1, wy = wave >> 1, m16 = lane & 15, quad = lane >> 4;
    bf16* Ct = (bf16*)LB;                 /* 64 x 128 bf16 half-tile */
    int rl = tid >> 4, cs = (tid & 15) * 8;
    int bI = row0 >> 10, sBase = row0 & 1023;
    #pragma unroll
    for (int h = 0; h < 2; h++) {
        if (wy == h) {
            #pragma unroll
            for (int j = 0; j < 4; j++) {
                int cl = wx * 64 + j * 16 + m16;
                int cg = col0 + cl;
                float bv = (cg < ND) ? bias[cg] : 0.f;
                bool ok = (cg < ND);
                #pragma unroll
                for (int i = 0; i < 4; i++)
                    #pragma unroll
                    for (int reg = 0; reg < 4; reg++)
                        Ct[(i * 16 + quad * 4 + reg) * 128 + cl] =
                            __float2bfloat16(ok ? (acc[i][j][reg] + bv) : 0.f);
            }
        }
        __syncthreads();
        if (zz < 2) {
            #pragma unroll
            for (int p = 0; p < 4; p++) {
                int row_l = p * 16 + rl;
                *(short8*)(out + (size_t)(row0 + h * 64 + row_l) * NDP + col0 + cs) =
                    *(const short8*)&Ct[row_l * 128 + cs];
            }
        } else {
            /* transposed store: valT[(b*NDP + c)*NT + s] */
            int cl2 = tid & 127, sh = tid >> 7;
            bf16* dst = valT + ((size_t)(bI * NDP + col0 + cl2)) * NT + sBase + h * 64 + sh * 32;
            #pragma unroll
            for (int kk = 0; kk < 8; kk++) {
                short4v o;
                #pragma unroll
                for (int e = 0; e < 4; e++)
                    ((bf16*)&o)[e] = Ct[(sh * 32 + kk * 4 + e) * 128 + cl2];
                *(short4v*)(dst + kk * 4) = o;
            }
        }
        __syncthreads();
    }
}

/* ---- MFMA S: bf16 out, coalesced epilogue ---- */
__global__ __launch_bounds__(256) void mfma_S(const bf16* __restrict__ key, const bf16* __restrict__ query,
                                              bf16* __restrict__ S) {
    __shared__ short LB[16384];
    short* As = LB;
    short* Bs = LB + 4096;
    f32x4 acc[4][4] = {};
    int bx, by, bz;
    xcd_swizzle(bx, by, bz);
    int z = bz;
    int row0 = bx * 128, col0 = by * 128;
    const bf16* kb = key + (size_t)z * NT * NDP;
    const bf16* qb = query + (size_t)z * NT * NDP;
    mfma_core(kb + (size_t)row0 * NDP, NDP, qb + (size_t)col0 * NDP, NDP, NDP / 32, As, Bs, acc);
    bf16* Sb = S + ((size_t)z << 20);
    const int tid = threadIdx.x, lane = tid & 63, wave = tid >> 6;
    const int wx = wave & 1, wy = wave >> 1, m16 = lane & 15, quad = lane >> 4;
    bf16* Ct = (bf16*)LB;
    int rl = tid >> 4, cs = (tid & 15) * 8;
    #pragma unroll
    for (int h = 0; h < 2; h++) {
        if (wy == h) {
            #pragma unroll
            for (int j = 0; j < 4; j++) {
                int cl = wx * 64 + j * 16 + m16;
                #pragma unroll
                for (int i = 0; i < 4; i++)
                    #pragma unroll
                    for (int reg = 0; reg < 4; reg++)
                        Ct[(i * 16 + quad * 4 + reg) * 128 + cl] = __float2bfloat16(acc[i][j][reg]);
            }
        }
        __syncthreads();
        #pragma unroll
        for (int p = 0; p < 4; p++) {
            int row_l = p * 16 + rl;
            *(short8*)(Sb + (((size_t)(row0 + h * 64 + row_l)) << 10) + col0 + cs) =
                *(const short8*)&Ct[row_l * 128 + cs];
        }
        __syncthreads();
    }
}

/* ---- double softmax: one wave per row, in-place P2 ---- */
__global__ __launch_bounds__(256) void attn_rows(bf16* __restrict__ S, float* __restrict__ att_out) {
    int gr = blockIdx.x * 4 + (threadIdx.x >> 6);
    int t = gr & 1023;
    int lane = threadIdx.x & 63;
    bf16* row = S + ((size_t)gr << 10) + lane * 16;
    short8 r0 = *(const short8*)row;
    short8 r1 = *(const short8*)(row + 8);
    float v[16];
    #pragma unroll
    for (int i = 0; i < 8; i++) { v[i] = b2f(((bf16*)&r0)[i]); v[8 + i] = b2f(((bf16*)&r1)[i]); }
    float m = -INFINITY;
    #pragma unroll
    for (int i = 0; i < 16; i++) m = fmaxf(m, v[i]);
    #pragma unroll
    for (int off = 32; off; off >>= 1) m = fmaxf(m, __shfl_xor(m, off, 64));
    float s1 = 0.f, s2 = 0.f, dg = 0.f;
    int tloc = t - lane * 16;
    #pragma unroll
    for (int i = 0; i < 16; i++) {
        float e1 = expf(v[i] - m);
        float e2 = expf((v[i] - m) * INV_SCALE);
        s1 += e1; s2 += e2;
        if (i == tloc) dg = e1;
        v[i] = e2;
    }
    #pragma unroll
    for (int off = 32; off; off >>= 1) {
        s1 += __shfl_xor(s1, off, 64);
        s2 += __shfl_xor(s2, off, 64);
        dg += __shfl_xor(dg, off, 64);
    }
    if (lane == 0) att_out[gr] = (1.f - dg / s1) * INV_SCALE;
    float inv2 = 1.f / s2;
    #pragma unroll
    for (int i = 0; i < 8; i++) {
        ((bf16*)&r0)[i] = __float2bfloat16(v[i] * inv2);
        ((bf16*)&r1)[i] = __float2bfloat16(v[8 + i] * inv2);
    }
    *(short8*)row = r0;
    *(short8*)(row + 8) = r1;
}

/* ---- MFMA PV: out = P2 @ V * mvec, fp32 out, LDS-restaged coalesced epilogue ---- */
__global__ __launch_bounds__(256) void mfma_PV(const bf16* __restrict__ S, const bf16* __restrict__ valueT,
                                               const float* __restrict__ mvec, float* __restrict__ outp) {
    __shared__ short LB[16384];
    short* As = LB;
    short* Bs = LB + 4096;
    f32x4 acc[4][4] = {};
    int bx, by, bz;
    xcd_swizzle(bx, by, bz);
    int z = bz;
    int row0 = bx * 128, col0 = by * 128;
    const bf16* P2 = S + ((size_t)z << 20);
    const bf16* Vt = valueT + (size_t)z * NDP * NT;
    mfma_core(P2 + (size_t)row0 * NT, NT, Vt + (size_t)col0 * NT, NT, NT / 32, As, Bs, acc);
    const int tid = threadIdx.x, lane = tid & 63, wave = tid >> 6;
    const int wx = wave & 1, wy = wave >> 1, m16 = lane & 15, quad = lane >> 4;
    float* Ct = (float*)LB;               /* 64 x 128 fp32 half-tile = 32 KB */
    int rl = tid >> 4, cs = (tid & 15) * 8;
    #pragma unroll
    for (int h = 0; h < 2; h++) {
        if (wy == h) {
            #pragma unroll
            for (int j = 0; j < 4; j++) {
                int cl = wx * 64 + j * 16 + m16;
                int cg = col0 + cl;
                float mm = (cg < ND) ? mvec[z * ND + cg] : 0.f;
                #pragma unroll
                for (int i = 0; i < 4; i++)
                    #pragma unroll
                    for (int reg = 0; reg < 4; reg++)
                        Ct[(i * 16 + quad * 4 + reg) * 128 + cl] = acc[i][j][reg] * mm;
            }
        }
        __syncthreads();
        #pragma unroll
        for (int p = 0; p < 4; p++) {
            int row_l = p * 16 + rl;
            int r = row0 + h * 64 + row_l;
            float* orow = outp + (size_t)(z * NT + r) * ND + col0 + cs;
            const float* src = &Ct[row_l * 128 + cs];
            if (col0 + cs + 8 <= ND) {
                *(f32x4*)orow = *(const f32x4*)src;
                *(f32x4*)(orow + 4) = *(const f32x4*)(src + 4);
            } else {
                #pragma unroll
                for (int e = 0; e < 8; e++)
                    if (col0 + cs + e < ND) orow[e] = src[e];
            }
        }
        __syncthreads();
    }
}

extern "C" void kernel_launch(void* const* d_in, const int* in_sizes, int n_in,
                              void* d_out, int out_size, void* d_ws, size_t ws_size,
                              hipStream_t stream) {
    const int*   words     = (const int*)d_in[0];
    const int*   pos       = (const int*)d_in[2];
    const int*   ner       = (const int*)d_in[3];
    const int*   subj_pos  = (const int*)d_in[4];
    const int*   obj_pos   = (const int*)d_in[5];
    const int*   chunks    = (const int*)d_in[6];
    const int*   on_path   = (const int*)d_in[7];
    const float* dep_feat  = (const float*)d_in[8];
    const float* emb_w     = (const float*)d_in[9];
    const float* pos_w     = (const float*)d_in[10];
    const float* ner_w     = (const float*)d_in[11];
    const float* chunk_w   = (const float*)d_in[12];
    const float* position_w= (const float*)d_in[13];
    const float* Wq_w      = (const float*)d_in[14];
    const float* Wq_b      = (const float*)d_in[15];
    const float* Wc_w      = (const float*)d_in[16];
    const float* Wc_b      = (const float*)d_in[17];
    const float* Wk_w      = (const float*)d_in[18];
    const float* Wk_b      = (const float*)d_in[19];
    const float* Wm_w      = (const float*)d_in[20];
    const float* Wm_b      = (const float*)d_in[21];
    const float* K_w       = (const float*)d_in[22];
    const float* K_b       = (const float*)d_in[23];
    const float* Q_w       = (const float*)d_in[24];
    const float* Q_b       = (const float*)d_in[25];
    const float* V_w       = (const float*)d_in[26];
    const float* V_b       = (const float*)d_in[27];

    float* out_main = (float*)d_out;
    float* out_att  = out_main + (size_t)NTOK * ND;

    /* ---- ws layout (~116 MB, unchanged) ---- */
    char* wp = (char*)d_ws;
    float* subj = (float*)wp; wp += (size_t)NB * ND * 4;
    float* qb   = (float*)wp; wp += (size_t)NB * ND * 4;   /* unused (kept for layout) */
    float* w2   = (float*)wp; wp += (size_t)NB * ND * 4;
    float* cb   = (float*)wp; wp += (size_t)NB * ND * 4;   /* unused (kept for layout) */
    float* mv   = (float*)wp; wp += (size_t)NB * ND * 4;
    float* klog = (float*)wp; wp += (size_t)NB * NT * 4;
    float* kbuf = (float*)wp; wp += (size_t)NB * NT * 4;
    float* part = (float*)wp; wp += (size_t)NB * TSP * NDP * 4;
    bf16* g     = (bf16*)wp;  wp += (size_t)NTOK * NDP * 2;
    bf16* Wt    = (bf16*)wp;  wp += (size_t)3 * NDP * NDP * 2;
    bf16* kqv   = (bf16*)wp;  wp += (size_t)3 * NTOK * NDP * 2;  /* key | query | (value region unused) */
    bf16* valT  = (bf16*)wp;  wp += (size_t)NTOK * NDP * 2;      /* Vt[b][c][s] */
    bf16* S     = (bf16*)wp;                                     /* NB<<20 bf16 = 32 MB */

    bf16* key   = kqv;
    bf16* query = kqv + (size_t)NTOK * NDP;
    (void)qb; (void)cb;

    transpose_w3<<<dim3(16, 16, 3), 256, 0, stream>>>(K_w, Q_w, V_w, Wt);

    /* phase A */
    build_g<<<NTOK, 128, 0, stream>>>(words, pos, ner, chunks, subj_pos, obj_pos,
                                      on_path, dep_feat, emb_w, pos_w, ner_w,
                                      chunk_w, position_w, g);
    pool_part<<<dim3(NB, TSP), 64, 0, stream>>>(g, subj_pos, part);
    fused_qw2<<<NB, 512, 0, stream>>>(part, Wq_w, Wq_b, Wc_w, Wc_b, Wk_w, subj, w2);
    compute_klog<<<NTOK / 4, 256, 0, stream>>>(g, w2, Wk_b, klog);
    softmax_k<<<NB, 256, 0, stream>>>(klog, kbuf);
    c_part<<<dim3(NB, TSP), 64, 0, stream>>>(g, kbuf, part);
    fused_m<<<NB, 512, 0, stream>>>(part, subj, Wm_w, Wm_b, mv);

    /* phase B */
    mfma_proj3<<<dim3(NTOK / 128, NDP / 128, 3), 256, 0, stream>>>(g, Wt, K_b, Q_b, V_b, kqv, valT);
    mfma_S<<<dim3(NT / 128, NT / 128, NB), 256, 0, stream>>>(key, query, S);
    attn_rows<<<NTOK / 4, 256, 0, stream>>>(S, out_att);
    mfma_PV<<<dim3(NT / 128, NDP / 128, NB), 256, 0, stream>>>(S, valT, mv, out_main);

    (void)in_sizes; (void)n_in; (void)out_size; (void)ws_size;
}

// Round 2
// 375.812 us; speedup vs baseline: 1.2335x; 1.2335x over previous
//
#include <hip/hip_runtime.h>
#include <hip/hip_bf16.h>

typedef __hip_bfloat16 bf16;
typedef __attribute__((ext_vector_type(8))) short short8;
typedef __attribute__((ext_vector_type(4))) short short4v;
typedef __attribute__((ext_vector_type(4))) float f32x4;

#define NB 16
#define NT 1024
#define ND 500
#define NDP 512               /* padded K/N for MFMA */
#define NTOK (NB * NT)
#define TSP 32                /* t split for pool/c kernels */
#define LSTR 32               /* LDS row stride in shorts */
#define INV_SCALE 0.04472135954999579f   /* 1/sqrt(500) */

__device__ __forceinline__ float b2f(bf16 x) { return __bfloat162float(x); }

__device__ __forceinline__ void gload_lds16(const bf16* g, short* l) {
    __builtin_amdgcn_global_load_lds((const __attribute__((address_space(1))) void*)g,
                                     (__attribute__((address_space(3))) void*)l, 16, 0, 0);
}

/* bijective XCD-aware swizzle of the linearized block id (nwg % 8 == 0 for all grids) */
__device__ __forceinline__ void xcd_swizzle(int& bx, int& by, int& bz) {
    int gx = gridDim.x, gy = gridDim.y;
    int nwg = gx * gy * (int)gridDim.z;
    int lin = blockIdx.x + gx * (blockIdx.y + gy * blockIdx.z);
    int cpx = nwg >> 3;
    int swz = (lin & 7) * cpx + (lin >> 3);
    bx = swz % gx;
    int r = swz / gx;
    by = r % gy;
    bz = r / gy;
}

/* =====================================================================
 * MFMA core: 128x128 tile, 4 waves (2x2), each wave 4x4 of 16x16x32.
 * 2-phase double-buffered pipeline: stage(next) overlaps MFMA(cur);
 * single vmcnt(0)+s_barrier per K-step.
 * ===================================================================== */
__device__ __forceinline__ void mfma_core(const bf16* __restrict__ Ab, int lda,
                                          const bf16* __restrict__ Bb, int ldb,
                                          int nsteps, short* As, short* Bs,
                                          f32x4 (&acc)[4][4]) {
    const int tid = threadIdx.x;
    const int lane = tid & 63;
    const int wave = tid >> 6;
    const int wy = wave >> 1, wx = wave & 1;
    const int m16 = lane & 15, quad = lane >> 4;
    const int srow = wave * 16 + (lane >> 2);
    const int sseg = lane & 3;
    const bf16* a0 = Ab + (size_t)srow * lda + sseg * 8;
    const bf16* a1 = a0 + (size_t)64 * lda;
    const bf16* b0 = Bb + (size_t)srow * ldb + sseg * 8;
    const bf16* b1 = b0 + (size_t)64 * ldb;
    short* aL0 = As + wave * 512;          /* wave-uniform LDS dests */
    short* aL1 = As + 2048 + wave * 512;
    short* bL0 = Bs + wave * 512;
    short* bL1 = Bs + 2048 + wave * 512;
    /* prologue: stage tile 0 into buffer 0 */
    gload_lds16(a0, aL0);
    gload_lds16(a1, aL1);
    gload_lds16(b0, bL0);
    gload_lds16(b1, bL1);
    asm volatile("s_waitcnt vmcnt(0)" ::: "memory");
    __builtin_amdgcn_s_barrier();
    for (int ks = 0; ks < nsteps; ks++) {
        const int cur = (ks & 1) * 8192;   /* buffer offset in shorts */
        const int nxt = 8192 - cur;
        if (ks + 1 < nsteps) {             /* prefetch next tile into other buffer */
            const int ko = (ks + 1) * 32;
            gload_lds16(a0 + ko, aL0 + nxt);
            gload_lds16(a1 + ko, aL1 + nxt);
            gload_lds16(b0 + ko, bL0 + nxt);
            gload_lds16(b1 + ko, bL1 + nxt);
        }
        short8 af[4], bfv[4];
        #pragma unroll
        for (int i = 0; i < 4; i++)
            af[i] = *(const short8*)&As[cur + (wy * 64 + i * 16 + m16) * LSTR + quad * 8];
        #pragma unroll
        for (int j = 0; j < 4; j++)
            bfv[j] = *(const short8*)&Bs[cur + (wx * 64 + j * 16 + m16) * LSTR + quad * 8];
        #pragma unroll
        for (int i = 0; i < 4; i++)
            #pragma unroll
            for (int j = 0; j < 4; j++)
                acc[i][j] = __builtin_amdgcn_mfma_f32_16x16x32_bf16(af[i], bfv[j], acc[i][j], 0, 0, 0);
        asm volatile("s_waitcnt vmcnt(0)" ::: "memory");
        __builtin_amdgcn_s_barrier();
    }
}

/* ---- W (500x500 fp32 [k][n]) -> Wt (512x512 bf16 [n][k]) ---- */
__global__ void transpose_w3(const float* __restrict__ WK, const float* __restrict__ WQ,
                             const float* __restrict__ WV, bf16* __restrict__ Wt_all) {
    const float* W = (blockIdx.z == 0) ? WK : (blockIdx.z == 1) ? WQ : WV;
    bf16* Wt = Wt_all + (size_t)blockIdx.z * NDP * NDP;
    __shared__ float t[32][33];
    int n0 = blockIdx.x * 32, k0 = blockIdx.y * 32;
    int a = threadIdx.x & 31, bq = threadIdx.x >> 5;
    #pragma unroll
    for (int it = 0; it < 4; it++) {
        int k = k0 + bq + it * 8, n = n0 + a;
        t[bq + it * 8][a] = (k < ND && n < ND) ? W[k * ND + n] : 0.f;
    }
    __syncthreads();
    #pragma unroll
    for (int it = 0; it < 4; it++) {
        int n = n0 + bq + it * 8;
        Wt[(size_t)n * NDP + k0 + a] = __float2bfloat16(t[a][bq + it * 8]);
    }
}

/* ---- build g (B,T,512) bf16 ---- */
__global__ void build_g(const int* __restrict__ words, const int* __restrict__ pos,
                        const int* __restrict__ ner, const int* __restrict__ chunks,
                        const int* __restrict__ subj_pos, const int* __restrict__ obj_pos,
                        const int* __restrict__ on_path, const float* __restrict__ dep_feat,
                        const float* __restrict__ emb_w, const float* __restrict__ pos_w,
                        const float* __restrict__ ner_w, const float* __restrict__ chunk_w,
                        const float* __restrict__ position_w, bf16* __restrict__ g) {
    int tok = blockIdx.x;
    int w = words[tok], p = pos[tok], n = ner[tok], ck = chunks[tok];
    int sp = subj_pos[tok], op = obj_pos[tok], onp = on_path[tok];
    bf16* gr = g + (size_t)tok * NDP;
    for (int d = threadIdx.x; d < NDP; d += blockDim.x) {
        float v;
        if      (d < 300) v = emb_w[(size_t)w * 300 + d];
        else if (d < 335) v = pos_w[p * 35 + (d - 300)];
        else if (d < 365) v = ner_w[n * 30 + (d - 335)];
        else if (d < 395) v = chunk_w[ck * 30 + (d - 365)];
        else if (d < 425) v = position_w[sp * 30 + (d - 395)];
        else if (d < 455) v = position_w[op * 30 + (d - 425)];
        else if (d == 455) v = (float)onp;
        else if (d < 500) v = dep_feat[(size_t)tok * 44 + (d - 456)];
        else              v = 0.f;
        gr[d] = __float2bfloat16(v);
    }
}

/* ---- subj max pool partials ---- */
__global__ void pool_part(const bf16* __restrict__ g, const int* __restrict__ subj_pos,
                          float* __restrict__ part) {
    int b = blockIdx.x, s = blockIdx.y;
    int c0 = threadIdx.x * 8;
    const bf16* gb = g + (size_t)b * NT * NDP + c0;
    const int* sp = subj_pos + b * NT;
    float mx[8];
    #pragma unroll
    for (int i = 0; i < 8; i++) mx[i] = -INFINITY;
    int t0 = s * (NT / TSP), t1 = t0 + (NT / TSP);
    for (int t = t0; t < t1; t++) {
        int masked = (sp[t] != 0);
        short8 v8 = *(const short8*)(gb + (size_t)t * NDP);
        #pragma unroll
        for (int i = 0; i < 8; i++) {
            float v = masked ? -1e12f : b2f(((bf16*)&v8)[i]);
            mx[i] = fmaxf(mx[i], v);
        }
    }
    float* pr = part + ((size_t)(b * TSP + s)) * NDP + c0;
    #pragma unroll
    for (int i = 0; i < 8; i++) pr[i] = mx[i];
}

/* =====================================================================
 * Parallel fused GEMVs: grid (NB, 4 d-chunks) x 512 thr.
 * Threads = 4 j-groups x 128 d-lanes; each thread sums 125 j's;
 * 4-way LDS reduce.  Stage-1 of each block does the vector prep
 * (pool/c reduce, x load) so no separate reduce kernels are needed.
 * ===================================================================== */

/* pool-reduce -> subj; q = relu(subj @ (Wq0+Wq1) + bq) */
__global__ __launch_bounds__(512) void gemv_q(const float* __restrict__ part,
                                              const float* __restrict__ Wq_w, const float* __restrict__ Wq_b,
                                              float* __restrict__ subj, float* __restrict__ qb) {
    int b = blockIdx.x, dch = blockIdx.y, tid = threadIdx.x;
    __shared__ float xs[512];
    __shared__ float red[512];
    float mx = -INFINITY;
    #pragma unroll
    for (int s = 0; s < TSP; s++) mx = fmaxf(mx, part[((size_t)(b * TSP + s)) * NDP + tid]);
    xs[tid] = (tid < ND) ? mx : 0.f;
    if (dch == 0 && tid < ND) subj[b * ND + tid] = mx;
    __syncthreads();
    int jg = tid >> 7, dl = tid & 127, d = dch * 128 + dl;
    float acc = 0.f;
    if (d < ND) {
        int j0 = jg * 125;
        const float* w0 = Wq_w + (size_t)j0 * ND + d;
        const float* w1 = w0 + (size_t)ND * ND;
        #pragma unroll 5
        for (int j = 0; j < 125; j++)
            acc += xs[j0 + j] * (w0[(size_t)j * ND] + w1[(size_t)j * ND]);
    }
    red[tid] = acc;
    __syncthreads();
    if (jg == 0 && d < ND) {
        float s = (red[dl] + red[128 + dl]) + (red[256 + dl] + red[384 + dl]);
        qb[b * ND + d] = fmaxf(s + Wq_b[d], 0.f);
    }
}

/* w2 = relu(q @ Wc0 + bc) * Wk */
__global__ __launch_bounds__(512) void gemv_w2(const float* __restrict__ qb,
                                               const float* __restrict__ Wc_w, const float* __restrict__ Wc_b,
                                               const float* __restrict__ Wk_w, float* __restrict__ w2) {
    int b = blockIdx.x, dch = blockIdx.y, tid = threadIdx.x;
    __shared__ float xs[512];
    __shared__ float red[512];
    xs[tid] = (tid < ND) ? qb[b * ND + tid] : 0.f;
    __syncthreads();
    int jg = tid >> 7, dl = tid & 127, d = dch * 128 + dl;
    float acc = 0.f;
    if (d < ND) {
        int j0 = jg * 125;
        const float* w0 = Wc_w + (size_t)j0 * ND + d;
        #pragma unroll 5
        for (int j = 0; j < 125; j++)
            acc += xs[j0 + j] * w0[(size_t)j * ND];
    }
    red[tid] = acc;
    __syncthreads();
    if (jg == 0 && d < ND) {
        float s = (red[dl] + red[128 + dl]) + (red[256 + dl] + red[384 + dl]);
        w2[b * ND + d] = fmaxf(s + Wc_b[d], 0.f) * Wk_w[d];
    }
}

/* c-reduce; m = relu(c @ Wm0 + subj @ (Wm1+Wm2) + bm) */
__global__ __launch_bounds__(512) void gemv_m(const float* __restrict__ part,
                                              const float* __restrict__ subj,
                                              const float* __restrict__ Wm_w, const float* __restrict__ Wm_b,
                                              float* __restrict__ mv) {
    int b = blockIdx.x, dch = blockIdx.y, tid = threadIdx.x;
    __shared__ float cs[512];
    __shared__ float ss[512];
    __shared__ float red[512];
    float a = 0.f;
    #pragma unroll
    for (int s = 0; s < TSP; s++) a += part[((size_t)(b * TSP + s)) * NDP + tid];
    cs[tid] = (tid < ND) ? a : 0.f;
    ss[tid] = (tid < ND) ? subj[b * ND + tid] : 0.f;
    __syncthreads();
    int jg = tid >> 7, dl = tid & 127, d = dch * 128 + dl;
    float acc = 0.f;
    if (d < ND) {
        int j0 = jg * 125;
        const float* w0 = Wm_w + (size_t)j0 * ND + d;
        const float* w1 = w0 + (size_t)ND * ND;
        const float* w2p = w0 + (size_t)2 * ND * ND;
        #pragma unroll 5
        for (int j = 0; j < 125; j++) {
            acc += cs[j0 + j] * w0[(size_t)j * ND];
            acc += ss[j0 + j] * (w1[(size_t)j * ND] + w2p[(size_t)j * ND]);
        }
    }
    red[tid] = acc;
    __syncthreads();
    if (jg == 0 && d < ND) {
        float s = (red[dl] + red[128 + dl]) + (red[256 + dl] + red[384 + dl]);
        mv[b * ND + d] = fmaxf(s + Wm_b[d], 0.f);
    }
}

/* ---- klog ---- */
__global__ void compute_klog(const bf16* __restrict__ g, const float* __restrict__ w2,
                             const float* __restrict__ Wk_b, float* __restrict__ klog) {
    int tok = blockIdx.x * 4 + (threadIdx.x >> 6);
    int lane = threadIdx.x & 63;
    int b = tok >> 10;
    const bf16* gr = g + (size_t)tok * NDP + lane * 8;
    const float* wr = w2 + b * ND + lane * 8;
    short8 v8 = *(const short8*)gr;
    float acc = 0.f;
    #pragma unroll
    for (int i = 0; i < 8; i++) acc += b2f(((bf16*)&v8)[i]) * wr[i];
    #pragma unroll
    for (int off = 32; off; off >>= 1) acc += __shfl_down(acc, off, 64);
    if (lane == 0) klog[tok] = acc + Wk_b[0];
}

/* ---- softmax over T ---- */
__global__ void softmax_k(const float* __restrict__ klog, float* __restrict__ k) {
    int b = blockIdx.x, tid = threadIdx.x;
    __shared__ float red[256];
    float m = -INFINITY;
    for (int t = tid; t < NT; t += 256) m = fmaxf(m, klog[b * NT + t]);
    red[tid] = m; __syncthreads();
    for (int s = 128; s; s >>= 1) { if (tid < s) red[tid] = fmaxf(red[tid], red[tid + s]); __syncthreads(); }
    m = red[0]; __syncthreads();
    float sum = 0.f;
    for (int t = tid; t < NT; t += 256) sum += expf(klog[b * NT + t] - m);
    red[tid] = sum; __syncthreads();
    for (int s = 128; s; s >>= 1) { if (tid < s) red[tid] += red[tid + s]; __syncthreads(); }
    float inv = 1.f / red[0];
    for (int t = tid; t < NT; t += 256) k[b * NT + t] = expf(klog[b * NT + t] - m) * inv;
}

/* ---- c = sum_t k*g partials ---- */
__global__ void c_part(const bf16* __restrict__ g, const float* __restrict__ k,
                       float* __restrict__ part) {
    int b = blockIdx.x, s = blockIdx.y;
    int c0 = threadIdx.x * 8;
    const bf16* gb = g + (size_t)b * NT * NDP + c0;
    const float* kb = k + b * NT;
    float acc[8] = {};
    int t0 = s * (NT / TSP), t1 = t0 + (NT / TSP);
    for (int t = t0; t < t1; t++) {
        float kv = kb[t];
        short8 v8 = *(const short8*)(gb + (size_t)t * NDP);
        #pragma unroll
        for (int i = 0; i < 8; i++) acc[i] += kv * b2f(((bf16*)&v8)[i]);
    }
    float* pr = part + ((size_t)(b * TSP + s)) * NDP + c0;
    #pragma unroll
    for (int i = 0; i < 8; i++) pr[i] = acc[i];
}

/* ---- MFMA projections K/Q/V. z==2 (value) writes TRANSPOSED Vt[b][c][s] directly ---- */
__global__ __launch_bounds__(256) void mfma_proj3(const bf16* __restrict__ g, const bf16* __restrict__ Wt_all,
                                                  const float* __restrict__ bK, const float* __restrict__ bQ,
                                                  const float* __restrict__ bV, bf16* __restrict__ kqv,
                                                  bf16* __restrict__ valT) {
    __shared__ short LB[16384];
    short* As = LB;
    short* Bs = LB + 4096;
    f32x4 acc[4][4] = {};
    int bx, by, bz;
    xcd_swizzle(bx, by, bz);
    const int zz = bz;
    const bf16* Wt = Wt_all + (size_t)zz * NDP * NDP;
    const float* bias = (zz == 0) ? bK : (zz == 1) ? bQ : bV;
    bf16* out = kqv + (size_t)zz * NTOK * NDP;
    int row0 = bx * 128, col0 = by * 128;
    mfma_core(g + (size_t)row0 * NDP, NDP, Wt + (size_t)col0 * NDP, NDP, NDP / 32, As, Bs, acc);
    const int tid = threadIdx.x, lane = tid & 63, wave = tid >> 6;
    const int wx = wave & 1, wy = wave >> 1, m16 = lane & 15, quad = lane >> 4;
    bf16* Ct = (bf16*)LB;                 /* 64 x 128 bf16 half-tile */
    int rl = tid >> 4, cs = (tid & 15) * 8;
    int bI = row0 >> 10, sBase = row0 & 1023;
    #pragma unroll
    for (int h = 0; h < 2; h++) {
        if (wy == h) {
            #pragma unroll
            for (int j = 0; j < 4; j++) {
                int cl = wx * 64 + j * 16 + m16;
                int cg = col0 + cl;
                float bv = (cg < ND) ? bias[cg] : 0.f;
                bool ok = (cg < ND);
                #pragma unroll
                for (int i = 0; i < 4; i++)
                    #pragma unroll
                    for (int reg = 0; reg < 4; reg++)
                        Ct[(i * 16 + quad * 4 + reg) * 128 + cl] =
                            __float2bfloat16(ok ? (acc[i][j][reg] + bv) : 0.f);
            }
        }
        __syncthreads();
        if (zz < 2) {
            #pragma unroll
            for (int p = 0; p < 4; p++) {
                int row_l = p * 16 + rl;
                *(short8*)(out + (size_t)(row0 + h * 64 + row_l) * NDP + col0 + cs) =
                    *(const short8*)&Ct[row_l * 128 + cs];
            }
        } else {
            /* transposed store: valT[(b*NDP + c)*NT + s] */
            int cl2 = tid & 127, sh = tid >> 7;
            bf16* dst = valT + ((size_t)(bI * NDP + col0 + cl2)) * NT + sBase + h * 64 + sh * 32;
            #pragma unroll
            for (int kk = 0; kk < 8; kk++) {
                short4v o;
                #pragma unroll
                for (int e = 0; e < 4; e++)
                    ((bf16*)&o)[e] = Ct[(sh * 32 + kk * 4 + e) * 128 + cl2];
                *(short4v*)(dst + kk * 4) = o;
            }
        }
        __syncthreads();
    }
}

/* ---- MFMA S: bf16 out, coalesced epilogue ---- */
__global__ __launch_bounds__(256) void mfma_S(const bf16* __restrict__ key, const bf16* __restrict__ query,
                                              bf16* __restrict__ S) {
    __shared__ short LB[16384];
    short* As = LB;
    short* Bs = LB + 4096;
    f32x4 acc[4][4] = {};
    int bx, by, bz;
    xcd_swizzle(bx, by, bz);
    int z = bz;
    int row0 = bx * 128, col0 = by * 128;
    const bf16* kb = key + (size_t)z * NT * NDP;
    const bf16* qb = query + (size_t)z * NT * NDP;
    mfma_core(kb + (size_t)row0 * NDP, NDP, qb + (size_t)col0 * NDP, NDP, NDP / 32, As, Bs, acc);
    bf16* Sb = S + ((size_t)z << 20);
    const int tid = threadIdx.x, lane = tid & 63, wave = tid >> 6;
    const int wx = wave & 1, wy = wave >> 1, m16 = lane & 15, quad = lane >> 4;
    bf16* Ct = (bf16*)LB;
    int rl = tid >> 4, cs = (tid & 15) * 8;
    #pragma unroll
    for (int h = 0; h < 2; h++) {
        if (wy == h) {
            #pragma unroll
            for (int j = 0; j < 4; j++) {
                int cl = wx * 64 + j * 16 + m16;
                #pragma unroll
                for (int i = 0; i < 4; i++)
                    #pragma unroll
                    for (int reg = 0; reg < 4; reg++)
                        Ct[(i * 16 + quad * 4 + reg) * 128 + cl] = __float2bfloat16(acc[i][j][reg]);
            }
        }
        __syncthreads();
        #pragma unroll
        for (int p = 0; p < 4; p++) {
            int row_l = p * 16 + rl;
            *(short8*)(Sb + (((size_t)(row0 + h * 64 + row_l)) << 10) + col0 + cs) =
                *(const short8*)&Ct[row_l * 128 + cs];
        }
        __syncthreads();
    }
}

/* ---- double softmax: one wave per row, in-place P2 ---- */
__global__ __launch_bounds__(256) void attn_rows(bf16* __restrict__ S, float* __restrict__ att_out) {
    int gr = blockIdx.x * 4 + (threadIdx.x >> 6);
    int t = gr & 1023;
    int lane = threadIdx.x & 63;
    bf16* row = S + ((size_t)gr << 10) + lane * 16;
    short8 r0 = *(const short8*)row;
    short8 r1 = *(const short8*)(row + 8);
    float v[16];
    #pragma unroll
    for (int i = 0; i < 8; i++) { v[i] = b2f(((bf16*)&r0)[i]); v[8 + i] = b2f(((bf16*)&r1)[i]); }
    float m = -INFINITY;
    #pragma unroll
    for (int i = 0; i < 16; i++) m = fmaxf(m, v[i]);
    #pragma unroll
    for (int off = 32; off; off >>= 1) m = fmaxf(m, __shfl_xor(m, off, 64));
    float s1 = 0.f, s2 = 0.f, dg = 0.f;
    int tloc = t - lane * 16;
    #pragma unroll
    for (int i = 0; i < 16; i++) {
        float e1 = expf(v[i] - m);
        float e2 = expf((v[i] - m) * INV_SCALE);
        s1 += e1; s2 += e2;
        if (i == tloc) dg = e1;
        v[i] = e2;
    }
    #pragma unroll
    for (int off = 32; off; off >>= 1) {
        s1 += __shfl_xor(s1, off, 64);
        s2 += __shfl_xor(s2, off, 64);
        dg += __shfl_xor(dg, off, 64);
    }
    if (lane == 0) att_out[gr] = (1.f - dg / s1) * INV_SCALE;
    float inv2 = 1.f / s2;
    #pragma unroll
    for (int i = 0; i < 8; i++) {
        ((bf16*)&r0)[i] = __float2bfloat16(v[i] * inv2);
        ((bf16*)&r1)[i] = __float2bfloat16(v[8 + i] * inv2);
    }
    *(short8*)row = r0;
    *(short8*)(row + 8) = r1;
}

/* ---- MFMA PV: out = P2 @ V * mvec, fp32 out, LDS-restaged coalesced epilogue ---- */
__global__ __launch_bounds__(256) void mfma_PV(const bf16* __restrict__ S, const bf16* __restrict__ valueT,
                                               const float* __restrict__ mvec, float* __restrict__ outp) {
    __shared__ short LB[16384];
    short* As = LB;
    short* Bs = LB + 4096;
    f32x4 acc[4][4] = {};
    int bx, by, bz;
    xcd_swizzle(bx, by, bz);
    int z = bz;
    int row0 = bx * 128, col0 = by * 128;
    const bf16* P2 = S + ((size_t)z << 20);
    const bf16* Vt = valueT + (size_t)z * NDP * NT;
    mfma_core(P2 + (size_t)row0 * NT, NT, Vt + (size_t)col0 * NT, NT, NT / 32, As, Bs, acc);
    const int tid = threadIdx.x, lane = tid & 63, wave = tid >> 6;
    const int wx = wave & 1, wy = wave >> 1, m16 = lane & 15, quad = lane >> 4;
    float* Ct = (float*)LB;               /* 64 x 128 fp32 half-tile = 32 KB */
    int rl = tid >> 4, cs = (tid & 15) * 8;
    #pragma unroll
    for (int h = 0; h < 2; h++) {
        if (wy == h) {
            #pragma unroll
            for (int j = 0; j < 4; j++) {
                int cl = wx * 64 + j * 16 + m16;
                int cg = col0 + cl;
                float mm = (cg < ND) ? mvec[z * ND + cg] : 0.f;
                #pragma unroll
                for (int i = 0; i < 4; i++)
                    #pragma unroll
                    for (int reg = 0; reg < 4; reg++)
                        Ct[(i * 16 + quad * 4 + reg) * 128 + cl] = acc[i][j][reg] * mm;
            }
        }
        __syncthreads();
        #pragma unroll
        for (int p = 0; p < 4; p++) {
            int row_l = p * 16 + rl;
            int r = row0 + h * 64 + row_l;
            float* orow = outp + (size_t)(z * NT + r) * ND + col0 + cs;
            const float* src = &Ct[row_l * 128 + cs];
            if (col0 + cs + 8 <= ND) {
                *(f32x4*)orow = *(const f32x4*)src;
                *(f32x4*)(orow + 4) = *(const f32x4*)(src + 4);
            } else {
                #pragma unroll
                for (int e = 0; e < 8; e++)
                    if (col0 + cs + e < ND) orow[e] = src[e];
            }
        }
        __syncthreads();
    }
}

extern "C" void kernel_launch(void* const* d_in, const int* in_sizes, int n_in,
                              void* d_out, int out_size, void* d_ws, size_t ws_size,
                              hipStream_t stream) {
    const int*   words     = (const int*)d_in[0];
    const int*   pos       = (const int*)d_in[2];
    const int*   ner       = (const int*)d_in[3];
    const int*   subj_pos  = (const int*)d_in[4];
    const int*   obj_pos   = (const int*)d_in[5];
    const int*   chunks    = (const int*)d_in[6];
    const int*   on_path   = (const int*)d_in[7];
    const float* dep_feat  = (const float*)d_in[8];
    const float* emb_w     = (const float*)d_in[9];
    const float* pos_w     = (const float*)d_in[10];
    const float* ner_w     = (const float*)d_in[11];
    const float* chunk_w   = (const float*)d_in[12];
    const float* position_w= (const float*)d_in[13];
    const float* Wq_w      = (const float*)d_in[14];
    const float* Wq_b      = (const float*)d_in[15];
    const float* Wc_w      = (const float*)d_in[16];
    const float* Wc_b      = (const float*)d_in[17];
    const float* Wk_w      = (const float*)d_in[18];
    const float* Wk_b      = (const float*)d_in[19];
    const float* Wm_w      = (const float*)d_in[20];
    const float* Wm_b      = (const float*)d_in[21];
    const float* K_w       = (const float*)d_in[22];
    const float* K_b       = (const float*)d_in[23];
    const float* Q_w       = (const float*)d_in[24];
    const float* Q_b       = (const float*)d_in[25];
    const float* V_w       = (const float*)d_in[26];
    const float* V_b       = (const float*)d_in[27];

    float* out_main = (float*)d_out;
    float* out_att  = out_main + (size_t)NTOK * ND;

    /* ---- ws layout (~116 MB, unchanged) ---- */
    char* wp = (char*)d_ws;
    float* subj = (float*)wp; wp += (size_t)NB * ND * 4;
    float* qb   = (float*)wp; wp += (size_t)NB * ND * 4;
    float* w2   = (float*)wp; wp += (size_t)NB * ND * 4;
    float* cb   = (float*)wp; wp += (size_t)NB * ND * 4;   /* unused (kept for layout) */
    float* mv   = (float*)wp; wp += (size_t)NB * ND * 4;
    float* klog = (float*)wp; wp += (size_t)NB * NT * 4;
    float* kbuf = (float*)wp; wp += (size_t)NB * NT * 4;
    float* part = (float*)wp; wp += (size_t)NB * TSP * NDP * 4;
    bf16* g     = (bf16*)wp;  wp += (size_t)NTOK * NDP * 2;
    bf16* Wt    = (bf16*)wp;  wp += (size_t)3 * NDP * NDP * 2;
    bf16* kqv   = (bf16*)wp;  wp += (size_t)3 * NTOK * NDP * 2;  /* key | query | (value region unused) */
    bf16* valT  = (bf16*)wp;  wp += (size_t)NTOK * NDP * 2;      /* Vt[b][c][s] */
    bf16* S     = (bf16*)wp;                                     /* NB<<20 bf16 = 32 MB */

    bf16* key   = kqv;
    bf16* query = kqv + (size_t)NTOK * NDP;
    (void)cb;

    transpose_w3<<<dim3(16, 16, 3), 256, 0, stream>>>(K_w, Q_w, V_w, Wt);

    /* phase A */
    build_g<<<NTOK, 128, 0, stream>>>(words, pos, ner, chunks, subj_pos, obj_pos,
                                      on_path, dep_feat, emb_w, pos_w, ner_w,
                                      chunk_w, position_w, g);
    pool_part<<<dim3(NB, TSP), 64, 0, stream>>>(g, subj_pos, part);
    gemv_q<<<dim3(NB, 4), 512, 0, stream>>>(part, Wq_w, Wq_b, subj, qb);
    gemv_w2<<<dim3(NB, 4), 512, 0, stream>>>(qb, Wc_w, Wc_b, Wk_w, w2);
    compute_klog<<<NTOK / 4, 256, 0, stream>>>(g, w2, Wk_b, klog);
    softmax_k<<<NB, 256, 0, stream>>>(klog, kbuf);
    c_part<<<dim3(NB, TSP), 64, 0, stream>>>(g, kbuf, part);
    gemv_m<<<dim3(NB, 4), 512, 0, stream>>>(part, subj, Wm_w, Wm_b, mv);

    /* phase B */
    mfma_proj3<<<dim3(NTOK / 128, NDP / 128, 3), 256, 0, stream>>>(g, Wt, K_b, Q_b, V_b, kqv, valT);
    mfma_S<<<dim3(NT / 128, NT / 128, NB), 256, 0, stream>>>(key, query, S);
    attn_rows<<<NTOK / 4, 256, 0, stream>>>(S, out_att);
    mfma_PV<<<dim3(NT / 128, NDP / 128, NB), 256, 0, stream>>>(S, valT, mv, out_main);

    (void)in_sizes; (void)n_in; (void)out_size; (void)ws_size;
}

// Round 3
// 356.536 us; speedup vs baseline: 1.3002x; 1.0541x over previous
//
#include <hip/hip_runtime.h>
#include <hip/hip_bf16.h>

typedef __hip_bfloat16 bf16;
typedef __attribute__((ext_vector_type(8))) short short8;
typedef __attribute__((ext_vector_type(4))) short short4v;
typedef __attribute__((ext_vector_type(4))) float f32x4;

#define NB 16
#define NT 1024
#define ND 500
#define NDP 512               /* padded K/N for MFMA */
#define NTOK (NB * NT)
#define TSP 32                /* t split for pool/c kernels */
#define LSTR 32               /* LDS row stride in shorts */
#define INV_SCALE 0.04472135954999579f   /* 1/sqrt(500) */

__device__ __forceinline__ float b2f(bf16 x) { return __bfloat162float(x); }

__device__ __forceinline__ void gload_lds16(const bf16* g, short* l) {
    __builtin_amdgcn_global_load_lds((const __attribute__((address_space(1))) void*)g,
                                     (__attribute__((address_space(3))) void*)l, 16, 0, 0);
}

/* =====================================================================
 * MFMA core: 128x128 tile, 4 waves (2x2), each wave 4x4 of 16x16x32.
 * 2-phase double-buffered pipeline: stage(next) overlaps MFMA(cur);
 * single vmcnt(0)+s_barrier per K-step.
 * ===================================================================== */
__device__ __forceinline__ void mfma_core(const bf16* __restrict__ Ab, int lda,
                                          const bf16* __restrict__ Bb, int ldb,
                                          int nsteps, short* As, short* Bs,
                                          f32x4 (&acc)[4][4]) {
    const int tid = threadIdx.x;
    const int lane = tid & 63;
    const int wave = tid >> 6;
    const int wy = wave >> 1, wx = wave & 1;
    const int m16 = lane & 15, quad = lane >> 4;
    const int srow = wave * 16 + (lane >> 2);
    const int sseg = lane & 3;
    const bf16* a0 = Ab + (size_t)srow * lda + sseg * 8;
    const bf16* a1 = a0 + (size_t)64 * lda;
    const bf16* b0 = Bb + (size_t)srow * ldb + sseg * 8;
    const bf16* b1 = b0 + (size_t)64 * ldb;
    short* aL0 = As + wave * 512;          /* wave-uniform LDS dests */
    short* aL1 = As + 2048 + wave * 512;
    short* bL0 = Bs + wave * 512;
    short* bL1 = Bs + 2048 + wave * 512;
    /* prologue: stage tile 0 into buffer 0 */
    gload_lds16(a0, aL0);
    gload_lds16(a1, aL1);
    gload_lds16(b0, bL0);
    gload_lds16(b1, bL1);
    asm volatile("s_waitcnt vmcnt(0)" ::: "memory");
    __builtin_amdgcn_s_barrier();
    for (int ks = 0; ks < nsteps; ks++) {
        const int cur = (ks & 1) * 8192;   /* buffer offset in shorts */
        const int nxt = 8192 - cur;
        if (ks + 1 < nsteps) {             /* prefetch next tile into other buffer */
            const int ko = (ks + 1) * 32;
            gload_lds16(a0 + ko, aL0 + nxt);
            gload_lds16(a1 + ko, aL1 + nxt);
            gload_lds16(b0 + ko, bL0 + nxt);
            gload_lds16(b1 + ko, bL1 + nxt);
        }
        short8 af[4], bfv[4];
        #pragma unroll
        for (int i = 0; i < 4; i++)
            af[i] = *(const short8*)&As[cur + (wy * 64 + i * 16 + m16) * LSTR + quad * 8];
        #pragma unroll
        for (int j = 0; j < 4; j++)
            bfv[j] = *(const short8*)&Bs[cur + (wx * 64 + j * 16 + m16) * LSTR + quad * 8];
        #pragma unroll
        for (int i = 0; i < 4; i++)
            #pragma unroll
            for (int j = 0; j < 4; j++)
                acc[i][j] = __builtin_amdgcn_mfma_f32_16x16x32_bf16(af[i], bfv[j], acc[i][j], 0, 0, 0);
        asm volatile("s_waitcnt vmcnt(0)" ::: "memory");
        __builtin_amdgcn_s_barrier();
    }
}

/* ---- W (500x500 fp32 [k][n]) -> Wt (512x512 bf16 [n][k]) ---- */
__global__ void transpose_w3(const float* __restrict__ WK, const float* __restrict__ WQ,
                             const float* __restrict__ WV, bf16* __restrict__ Wt_all) {
    const float* W = (blockIdx.z == 0) ? WK : (blockIdx.z == 1) ? WQ : WV;
    bf16* Wt = Wt_all + (size_t)blockIdx.z * NDP * NDP;
    __shared__ float t[32][33];
    int n0 = blockIdx.x * 32, k0 = blockIdx.y * 32;
    int a = threadIdx.x & 31, bq = threadIdx.x >> 5;
    #pragma unroll
    for (int it = 0; it < 4; it++) {
        int k = k0 + bq + it * 8, n = n0 + a;
        t[bq + it * 8][a] = (k < ND && n < ND) ? W[k * ND + n] : 0.f;
    }
    __syncthreads();
    #pragma unroll
    for (int it = 0; it < 4; it++) {
        int n = n0 + bq + it * 8;
        Wt[(size_t)n * NDP + k0 + a] = __float2bfloat16(t[a][bq + it * 8]);
    }
}

/* ---- build g (B,T,512) bf16 ---- */
__global__ void build_g(const int* __restrict__ words, const int* __restrict__ pos,
                        const int* __restrict__ ner, const int* __restrict__ chunks,
                        const int* __restrict__ subj_pos, const int* __restrict__ obj_pos,
                        const int* __restrict__ on_path, const float* __restrict__ dep_feat,
                        const float* __restrict__ emb_w, const float* __restrict__ pos_w,
                        const float* __restrict__ ner_w, const float* __restrict__ chunk_w,
                        const float* __restrict__ position_w, bf16* __restrict__ g) {
    int tok = blockIdx.x;
    int w = words[tok], p = pos[tok], n = ner[tok], ck = chunks[tok];
    int sp = subj_pos[tok], op = obj_pos[tok], onp = on_path[tok];
    bf16* gr = g + (size_t)tok * NDP;
    for (int d = threadIdx.x; d < NDP; d += blockDim.x) {
        float v;
        if      (d < 300) v = emb_w[(size_t)w * 300 + d];
        else if (d < 335) v = pos_w[p * 35 + (d - 300)];
        else if (d < 365) v = ner_w[n * 30 + (d - 335)];
        else if (d < 395) v = chunk_w[ck * 30 + (d - 365)];
        else if (d < 425) v = position_w[sp * 30 + (d - 395)];
        else if (d < 455) v = position_w[op * 30 + (d - 425)];
        else if (d == 455) v = (float)onp;
        else if (d < 500) v = dep_feat[(size_t)tok * 44 + (d - 456)];
        else              v = 0.f;
        gr[d] = __float2bfloat16(v);
    }
}

/* ---- subj max pool partials ---- */
__global__ void pool_part(const bf16* __restrict__ g, const int* __restrict__ subj_pos,
                          float* __restrict__ part) {
    int b = blockIdx.x, s = blockIdx.y;
    int c0 = threadIdx.x * 8;
    const bf16* gb = g + (size_t)b * NT * NDP + c0;
    const int* sp = subj_pos + b * NT;
    float mx[8];
    #pragma unroll
    for (int i = 0; i < 8; i++) mx[i] = -INFINITY;
    int t0 = s * (NT / TSP), t1 = t0 + (NT / TSP);
    for (int t = t0; t < t1; t++) {
        int masked = (sp[t] != 0);
        short8 v8 = *(const short8*)(gb + (size_t)t * NDP);
        #pragma unroll
        for (int i = 0; i < 8; i++) {
            float v = masked ? -1e12f : b2f(((bf16*)&v8)[i]);
            mx[i] = fmaxf(mx[i], v);
        }
    }
    float* pr = part + ((size_t)(b * TSP + s)) * NDP + c0;
    #pragma unroll
    for (int i = 0; i < 8; i++) pr[i] = mx[i];
}

/* =====================================================================
 * Parallel fused GEMVs: grid (NB, 4 d-chunks) x 512 thr.
 * ===================================================================== */

/* pool-reduce -> subj; q = relu(subj @ (Wq0+Wq1) + bq) */
__global__ __launch_bounds__(512) void gemv_q(const float* __restrict__ part,
                                              const float* __restrict__ Wq_w, const float* __restrict__ Wq_b,
                                              float* __restrict__ subj, float* __restrict__ qb) {
    int b = blockIdx.x, dch = blockIdx.y, tid = threadIdx.x;
    __shared__ float xs[512];
    __shared__ float red[512];
    float mx = -INFINITY;
    #pragma unroll
    for (int s = 0; s < TSP; s++) mx = fmaxf(mx, part[((size_t)(b * TSP + s)) * NDP + tid]);
    xs[tid] = (tid < ND) ? mx : 0.f;
    if (dch == 0 && tid < ND) subj[b * ND + tid] = mx;
    __syncthreads();
    int jg = tid >> 7, dl = tid & 127, d = dch * 128 + dl;
    float acc = 0.f;
    if (d < ND) {
        int j0 = jg * 125;
        const float* w0 = Wq_w + (size_t)j0 * ND + d;
        const float* w1 = w0 + (size_t)ND * ND;
        #pragma unroll 5
        for (int j = 0; j < 125; j++)
            acc += xs[j0 + j] * (w0[(size_t)j * ND] + w1[(size_t)j * ND]);
    }
    red[tid] = acc;
    __syncthreads();
    if (jg == 0 && d < ND) {
        float s = (red[dl] + red[128 + dl]) + (red[256 + dl] + red[384 + dl]);
        qb[b * ND + d] = fmaxf(s + Wq_b[d], 0.f);
    }
}

/* w2 = relu(q @ Wc0 + bc) * Wk */
__global__ __launch_bounds__(512) void gemv_w2(const float* __restrict__ qb,
                                               const float* __restrict__ Wc_w, const float* __restrict__ Wc_b,
                                               const float* __restrict__ Wk_w, float* __restrict__ w2) {
    int b = blockIdx.x, dch = blockIdx.y, tid = threadIdx.x;
    __shared__ float xs[512];
    __shared__ float red[512];
    xs[tid] = (tid < ND) ? qb[b * ND + tid] : 0.f;
    __syncthreads();
    int jg = tid >> 7, dl = tid & 127, d = dch * 128 + dl;
    float acc = 0.f;
    if (d < ND) {
        int j0 = jg * 125;
        const float* w0 = Wc_w + (size_t)j0 * ND + d;
        #pragma unroll 5
        for (int j = 0; j < 125; j++)
            acc += xs[j0 + j] * w0[(size_t)j * ND];
    }
    red[tid] = acc;
    __syncthreads();
    if (jg == 0 && d < ND) {
        float s = (red[dl] + red[128 + dl]) + (red[256 + dl] + red[384 + dl]);
        w2[b * ND + d] = fmaxf(s + Wc_b[d], 0.f) * Wk_w[d];
    }
}

/* c-reduce; m = relu(c @ Wm0 + subj @ (Wm1+Wm2) + bm) */
__global__ __launch_bounds__(512) void gemv_m(const float* __restrict__ part,
                                              const float* __restrict__ subj,
                                              const float* __restrict__ Wm_w, const float* __restrict__ Wm_b,
                                              float* __restrict__ mv) {
    int b = blockIdx.x, dch = blockIdx.y, tid = threadIdx.x;
    __shared__ float cs[512];
    __shared__ float ss[512];
    __shared__ float red[512];
    float a = 0.f;
    #pragma unroll
    for (int s = 0; s < TSP; s++) a += part[((size_t)(b * TSP + s)) * NDP + tid];
    cs[tid] = (tid < ND) ? a : 0.f;
    ss[tid] = (tid < ND) ? subj[b * ND + tid] : 0.f;
    __syncthreads();
    int jg = tid >> 7, dl = tid & 127, d = dch * 128 + dl;
    float acc = 0.f;
    if (d < ND) {
        int j0 = jg * 125;
        const float* w0 = Wm_w + (size_t)j0 * ND + d;
        const float* w1 = w0 + (size_t)ND * ND;
        const float* w2p = w0 + (size_t)2 * ND * ND;
        #pragma unroll 5
        for (int j = 0; j < 125; j++) {
            acc += cs[j0 + j] * w0[(size_t)j * ND];
            acc += ss[j0 + j] * (w1[(size_t)j * ND] + w2p[(size_t)j * ND]);
        }
    }
    red[tid] = acc;
    __syncthreads();
    if (jg == 0 && d < ND) {
        float s = (red[dl] + red[128 + dl]) + (red[256 + dl] + red[384 + dl]);
        mv[b * ND + d] = fmaxf(s + Wm_b[d], 0.f);
    }
}

/* ---- klog ---- */
__global__ void compute_klog(const bf16* __restrict__ g, const float* __restrict__ w2,
                             const float* __restrict__ Wk_b, float* __restrict__ klog) {
    int tok = blockIdx.x * 4 + (threadIdx.x >> 6);
    int lane = threadIdx.x & 63;
    int b = tok >> 10;
    const bf16* gr = g + (size_t)tok * NDP + lane * 8;
    const float* wr = w2 + b * ND + lane * 8;
    short8 v8 = *(const short8*)gr;
    float acc = 0.f;
    #pragma unroll
    for (int i = 0; i < 8; i++) acc += b2f(((bf16*)&v8)[i]) * wr[i];
    #pragma unroll
    for (int off = 32; off; off >>= 1) acc += __shfl_down(acc, off, 64);
    if (lane == 0) klog[tok] = acc + Wk_b[0];
}

/* ---- softmax over T ---- */
__global__ void softmax_k(const float* __restrict__ klog, float* __restrict__ k) {
    int b = blockIdx.x, tid = threadIdx.x;
    __shared__ float red[256];
    float m = -INFINITY;
    for (int t = tid; t < NT; t += 256) m = fmaxf(m, klog[b * NT + t]);
    red[tid] = m; __syncthreads();
    for (int s = 128; s; s >>= 1) { if (tid < s) red[tid] = fmaxf(red[tid], red[tid + s]); __syncthreads(); }
    m = red[0]; __syncthreads();
    float sum = 0.f;
    for (int t = tid; t < NT; t += 256) sum += expf(klog[b * NT + t] - m);
    red[tid] = sum; __syncthreads();
    for (int s = 128; s; s >>= 1) { if (tid < s) red[tid] += red[tid + s]; __syncthreads(); }
    float inv = 1.f / red[0];
    for (int t = tid; t < NT; t += 256) k[b * NT + t] = expf(klog[b * NT + t] - m) * inv;
}

/* ---- c = sum_t k*g partials ---- */
__global__ void c_part(const bf16* __restrict__ g, const float* __restrict__ k,
                       float* __restrict__ part) {
    int b = blockIdx.x, s = blockIdx.y;
    int c0 = threadIdx.x * 8;
    const bf16* gb = g + (size_t)b * NT * NDP + c0;
    const float* kb = k + b * NT;
    float acc[8] = {};
    int t0 = s * (NT / TSP), t1 = t0 + (NT / TSP);
    for (int t = t0; t < t1; t++) {
        float kv = kb[t];
        short8 v8 = *(const short8*)(gb + (size_t)t * NDP);
        #pragma unroll
        for (int i = 0; i < 8; i++) acc[i] += kv * b2f(((bf16*)&v8)[i]);
    }
    float* pr = part + ((size_t)(b * TSP + s)) * NDP + c0;
    #pragma unroll
    for (int i = 0; i < 8; i++) pr[i] = acc[i];
}

/* ---- MFMA projections K/Q/V, natural grid (bx innermost: g-panel sharers
 *      sit at stride 128 = same XCD -> L2 reuse; round-0 measured 21 MB). ---- */
__global__ __launch_bounds__(256) void mfma_proj3(const bf16* __restrict__ g, const bf16* __restrict__ Wt_all,
                                                  const float* __restrict__ bK, const float* __restrict__ bQ,
                                                  const float* __restrict__ bV, bf16* __restrict__ kqv,
                                                  bf16* __restrict__ valT) {
    __shared__ short LB[16384];
    short* As = LB;
    short* Bs = LB + 4096;
    f32x4 acc[4][4] = {};
    const int zz = blockIdx.z;
    const bf16* Wt = Wt_all + (size_t)zz * NDP * NDP;
    const float* bias = (zz == 0) ? bK : (zz == 1) ? bQ : bV;
    bf16* out = kqv + (size_t)zz * NTOK * NDP;
    int row0 = blockIdx.x * 128, col0 = blockIdx.y * 128;
    mfma_core(g + (size_t)row0 * NDP, NDP, Wt + (size_t)col0 * NDP, NDP, NDP / 32, As, Bs, acc);
    const int tid = threadIdx.x, lane = tid & 63, wave = tid >> 6;
    const int wx = wave & 1, wy = wave >> 1, m16 = lane & 15, quad = lane >> 4;
    bf16* Ct = (bf16*)LB;                 /* 64 x 128 bf16 half-tile */
    int rl = tid >> 4, cs = (tid & 15) * 8;
    int bI = row0 >> 10, sBase = row0 & 1023;
    #pragma unroll
    for (int h = 0; h < 2; h++) {
        if (wy == h) {
            #pragma unroll
            for (int j = 0; j < 4; j++) {
                int cl = wx * 64 + j * 16 + m16;
                int cg = col0 + cl;
                float bv = (cg < ND) ? bias[cg] : 0.f;
                bool ok = (cg < ND);
                #pragma unroll
                for (int i = 0; i < 4; i++)
                    #pragma unroll
                    for (int reg = 0; reg < 4; reg++)
                        Ct[(i * 16 + quad * 4 + reg) * 128 + cl] =
                            __float2bfloat16(ok ? (acc[i][j][reg] + bv) : 0.f);
            }
        }
        __syncthreads();
        if (zz < 2) {
            #pragma unroll
            for (int p = 0; p < 4; p++) {
                int row_l = p * 16 + rl;
                *(short8*)(out + (size_t)(row0 + h * 64 + row_l) * NDP + col0 + cs) =
                    *(const short8*)&Ct[row_l * 128 + cs];
            }
        } else {
            /* transposed store: valT[(b*NDP + c)*NT + s] */
            int cl2 = tid & 127, sh = tid >> 7;
            bf16* dst = valT + ((size_t)(bI * NDP + col0 + cl2)) * NT + sBase + h * 64 + sh * 32;
            #pragma unroll
            for (int kk = 0; kk < 8; kk++) {
                short4v o;
                #pragma unroll
                for (int e = 0; e < 4; e++)
                    ((bf16*)&o)[e] = Ct[(sh * 32 + kk * 4 + e) * 128 + cl2];
                *(short4v*)(dst + kk * 4) = o;
            }
        }
        __syncthreads();
    }
}

/* ---- MFMA S: 1-D grid, each XCD owns whole z-batches (key+query = 2MB < 4MB L2) ---- */
__global__ __launch_bounds__(256) void mfma_S(const bf16* __restrict__ key, const bf16* __restrict__ query,
                                              bf16* __restrict__ S) {
    __shared__ short LB[16384];
    short* As = LB;
    short* Bs = LB + 4096;
    f32x4 acc[4][4] = {};
    /* lin = xcd + 8*(i + 64*zh); z = xcd + 8*zh; i = bx + 8*by */
    int lin = blockIdx.x;
    int xcd = lin & 7, j = lin >> 3;
    int i = j & 63, z = xcd + 8 * (j >> 6);
    int bx = i & 7, by = i >> 3;
    int row0 = bx * 128, col0 = by * 128;
    const bf16* kb = key + (size_t)z * NT * NDP;
    const bf16* qb = query + (size_t)z * NT * NDP;
    mfma_core(kb + (size_t)row0 * NDP, NDP, qb + (size_t)col0 * NDP, NDP, NDP / 32, As, Bs, acc);
    bf16* Sb = S + ((size_t)z << 20);
    const int tid = threadIdx.x, lane = tid & 63, wave = tid >> 6;
    const int wx = wave & 1, wy = wave >> 1, m16 = lane & 15, quad = lane >> 4;
    bf16* Ct = (bf16*)LB;
    int rl = tid >> 4, cs = (tid & 15) * 8;
    #pragma unroll
    for (int h = 0; h < 2; h++) {
        if (wy == h) {
            #pragma unroll
            for (int j2 = 0; j2 < 4; j2++) {
                int cl = wx * 64 + j2 * 16 + m16;
                #pragma unroll
                for (int i2 = 0; i2 < 4; i2++)
                    #pragma unroll
                    for (int reg = 0; reg < 4; reg++)
                        Ct[(i2 * 16 + quad * 4 + reg) * 128 + cl] = __float2bfloat16(acc[i2][j2][reg]);
            }
        }
        __syncthreads();
        #pragma unroll
        for (int p = 0; p < 4; p++) {
            int row_l = p * 16 + rl;
            *(short8*)(Sb + (((size_t)(row0 + h * 64 + row_l)) << 10) + col0 + cs) =
                *(const short8*)&Ct[row_l * 128 + cs];
        }
        __syncthreads();
    }
}

/* ---- double softmax: one wave per row, in-place P2 ---- */
__global__ __launch_bounds__(256) void attn_rows(bf16* __restrict__ S, float* __restrict__ att_out) {
    int gr = blockIdx.x * 4 + (threadIdx.x >> 6);
    int t = gr & 1023;
    int lane = threadIdx.x & 63;
    bf16* row = S + ((size_t)gr << 10) + lane * 16;
    short8 r0 = *(const short8*)row;
    short8 r1 = *(const short8*)(row + 8);
    float v[16];
    #pragma unroll
    for (int i = 0; i < 8; i++) { v[i] = b2f(((bf16*)&r0)[i]); v[8 + i] = b2f(((bf16*)&r1)[i]); }
    float m = -INFINITY;
    #pragma unroll
    for (int i = 0; i < 16; i++) m = fmaxf(m, v[i]);
    #pragma unroll
    for (int off = 32; off; off >>= 1) m = fmaxf(m, __shfl_xor(m, off, 64));
    float s1 = 0.f, s2 = 0.f, dg = 0.f;
    int tloc = t - lane * 16;
    #pragma unroll
    for (int i = 0; i < 16; i++) {
        float e1 = expf(v[i] - m);
        float e2 = expf((v[i] - m) * INV_SCALE);
        s1 += e1; s2 += e2;
        if (i == tloc) dg = e1;
        v[i] = e2;
    }
    #pragma unroll
    for (int off = 32; off; off >>= 1) {
        s1 += __shfl_xor(s1, off, 64);
        s2 += __shfl_xor(s2, off, 64);
        dg += __shfl_xor(dg, off, 64);
    }
    if (lane == 0) att_out[gr] = (1.f - dg / s1) * INV_SCALE;
    float inv2 = 1.f / s2;
    #pragma unroll
    for (int i = 0; i < 8; i++) {
        ((bf16*)&r0)[i] = __float2bfloat16(v[i] * inv2);
        ((bf16*)&r1)[i] = __float2bfloat16(v[8 + i] * inv2);
    }
    *(short8*)row = r0;
    *(short8*)(row + 8) = r1;
}

/* ---- MFMA PV: 1-D grid, each XCD owns whole z-batches (P2 2MB + Vt 1MB < 4MB L2) ---- */
__global__ __launch_bounds__(256) void mfma_PV(const bf16* __restrict__ S, const bf16* __restrict__ valueT,
                                               const float* __restrict__ mvec, float* __restrict__ outp) {
    __shared__ short LB[16384];
    short* As = LB;
    short* Bs = LB + 4096;
    f32x4 acc[4][4] = {};
    /* lin = xcd + 8*(i + 32*zh); z = xcd + 8*zh; i = bx + 8*by */
    int lin = blockIdx.x;
    int xcd = lin & 7, j = lin >> 3;
    int i = j & 31, z = xcd + 8 * (j >> 5);
    int bx = i & 7, by = i >> 3;
    int row0 = bx * 128, col0 = by * 128;
    const bf16* P2 = S + ((size_t)z << 20);
    const bf16* Vt = valueT + (size_t)z * NDP * NT;
    mfma_core(P2 + (size_t)row0 * NT, NT, Vt + (size_t)col0 * NT, NT, NT / 32, As, Bs, acc);
    const int tid = threadIdx.x, lane = tid & 63, wave = tid >> 6;
    const int wx = wave & 1, wy = wave >> 1, m16 = lane & 15, quad = lane >> 4;
    float* Ct = (float*)LB;               /* 64 x 128 fp32 half-tile = 32 KB */
    int rl = tid >> 4, cs = (tid & 15) * 8;
    #pragma unroll
    for (int h = 0; h < 2; h++) {
        if (wy == h) {
            #pragma unroll
            for (int j2 = 0; j2 < 4; j2++) {
                int cl = wx * 64 + j2 * 16 + m16;
                int cg = col0 + cl;
                float mm = (cg < ND) ? mvec[z * ND + cg] : 0.f;
                #pragma unroll
                for (int i2 = 0; i2 < 4; i2++)
                    #pragma unroll
                    for (int reg = 0; reg < 4; reg++)
                        Ct[(i2 * 16 + quad * 4 + reg) * 128 + cl] = acc[i2][j2][reg] * mm;
            }
        }
        __syncthreads();
        #pragma unroll
        for (int p = 0; p < 4; p++) {
            int row_l = p * 16 + rl;
            int r = row0 + h * 64 + row_l;
            float* orow = outp + (size_t)(z * NT + r) * ND + col0 + cs;
            const float* src = &Ct[row_l * 128 + cs];
            if (col0 + cs + 8 <= ND) {
                *(f32x4*)orow = *(const f32x4*)src;
                *(f32x4*)(orow + 4) = *(const f32x4*)(src + 4);
            } else {
                #pragma unroll
                for (int e = 0; e < 8; e++)
                    if (col0 + cs + e < ND) orow[e] = src[e];
            }
        }
        __syncthreads();
    }
}

extern "C" void kernel_launch(void* const* d_in, const int* in_sizes, int n_in,
                              void* d_out, int out_size, void* d_ws, size_t ws_size,
                              hipStream_t stream) {
    const int*   words     = (const int*)d_in[0];
    const int*   pos       = (const int*)d_in[2];
    const int*   ner       = (const int*)d_in[3];
    const int*   subj_pos  = (const int*)d_in[4];
    const int*   obj_pos   = (const int*)d_in[5];
    const int*   chunks    = (const int*)d_in[6];
    const int*   on_path   = (const int*)d_in[7];
    const float* dep_feat  = (const float*)d_in[8];
    const float* emb_w     = (const float*)d_in[9];
    const float* pos_w     = (const float*)d_in[10];
    const float* ner_w     = (const float*)d_in[11];
    const float* chunk_w   = (const float*)d_in[12];
    const float* position_w= (const float*)d_in[13];
    const float* Wq_w      = (const float*)d_in[14];
    const float* Wq_b      = (const float*)d_in[15];
    const float* Wc_w      = (const float*)d_in[16];
    const float* Wc_b      = (const float*)d_in[17];
    const float* Wk_w      = (const float*)d_in[18];
    const float* Wk_b      = (const float*)d_in[19];
    const float* Wm_w      = (const float*)d_in[20];
    const float* Wm_b      = (const float*)d_in[21];
    const float* K_w       = (const float*)d_in[22];
    const float* K_b       = (const float*)d_in[23];
    const float* Q_w       = (const float*)d_in[24];
    const float* Q_b       = (const float*)d_in[25];
    const float* V_w       = (const float*)d_in[26];
    const float* V_b       = (const float*)d_in[27];

    float* out_main = (float*)d_out;
    float* out_att  = out_main + (size_t)NTOK * ND;

    /* ---- ws layout (~116 MB, unchanged) ---- */
    char* wp = (char*)d_ws;
    float* subj = (float*)wp; wp += (size_t)NB * ND * 4;
    float* qb   = (float*)wp; wp += (size_t)NB * ND * 4;
    float* w2   = (float*)wp; wp += (size_t)NB * ND * 4;
    float* cb   = (float*)wp; wp += (size_t)NB * ND * 4;   /* unused (kept for layout) */
    float* mv   = (float*)wp; wp += (size_t)NB * ND * 4;
    float* klog = (float*)wp; wp += (size_t)NB * NT * 4;
    float* kbuf = (float*)wp; wp += (size_t)NB * NT * 4;
    float* part = (float*)wp; wp += (size_t)NB * TSP * NDP * 4;
    bf16* g     = (bf16*)wp;  wp += (size_t)NTOK * NDP * 2;
    bf16* Wt    = (bf16*)wp;  wp += (size_t)3 * NDP * NDP * 2;
    bf16* kqv   = (bf16*)wp;  wp += (size_t)3 * NTOK * NDP * 2;  /* key | query | (value region unused) */
    bf16* valT  = (bf16*)wp;  wp += (size_t)NTOK * NDP * 2;      /* Vt[b][c][s] */
    bf16* S     = (bf16*)wp;                                     /* NB<<20 bf16 = 32 MB */

    bf16* key   = kqv;
    bf16* query = kqv + (size_t)NTOK * NDP;
    (void)cb;

    transpose_w3<<<dim3(16, 16, 3), 256, 0, stream>>>(K_w, Q_w, V_w, Wt);

    /* phase A */
    build_g<<<NTOK, 128, 0, stream>>>(words, pos, ner, chunks, subj_pos, obj_pos,
                                      on_path, dep_feat, emb_w, pos_w, ner_w,
                                      chunk_w, position_w, g);
    pool_part<<<dim3(NB, TSP), 64, 0, stream>>>(g, subj_pos, part);
    gemv_q<<<dim3(NB, 4), 512, 0, stream>>>(part, Wq_w, Wq_b, subj, qb);
    gemv_w2<<<dim3(NB, 4), 512, 0, stream>>>(qb, Wc_w, Wc_b, Wk_w, w2);
    compute_klog<<<NTOK / 4, 256, 0, stream>>>(g, w2, Wk_b, klog);
    softmax_k<<<NB, 256, 0, stream>>>(klog, kbuf);
    c_part<<<dim3(NB, TSP), 64, 0, stream>>>(g, kbuf, part);
    gemv_m<<<dim3(NB, 4), 512, 0, stream>>>(part, subj, Wm_w, Wm_b, mv);

    /* phase B */
    mfma_proj3<<<dim3(NTOK / 128, NDP / 128, 3), 256, 0, stream>>>(g, Wt, K_b, Q_b, V_b, kqv, valT);
    mfma_S<<<1024, 256, 0, stream>>>(key, query, S);
    attn_rows<<<NTOK / 4, 256, 0, stream>>>(S, out_att);
    mfma_PV<<<512, 256, 0, stream>>>(S, valT, mv, out_main);

    (void)in_sizes; (void)n_in; (void)out_size; (void)ws_size;
}

// Round 4
// 345.302 us; speedup vs baseline: 1.3425x; 1.0325x over previous
//
#include <hip/hip_runtime.h>
#include <hip/hip_bf16.h>

typedef __hip_bfloat16 bf16;
typedef __attribute__((ext_vector_type(8))) short short8;
typedef __attribute__((ext_vector_type(4))) short short4v;
typedef __attribute__((ext_vector_type(4))) float f32x4;

#define NB 16
#define NT 1024
#define ND 500
#define NDP 512               /* padded K/N for MFMA */
#define NTOK (NB * NT)
#define TSP 32                /* t split for pool/c kernels */
#define INV_SCALE 0.04472135954999579f   /* 1/sqrt(500) */

__device__ __forceinline__ float b2f(bf16 x) { return __bfloat162float(x); }

__device__ __forceinline__ void gload_lds16(const bf16* g, short* l) {
    __builtin_amdgcn_global_load_lds((const __attribute__((address_space(1))) void*)g,
                                     (__attribute__((address_space(3))) void*)l, 16, 0, 0);
}

/* =====================================================================
 * MFMA core: 128x128 tile, 4 waves (2x2), each wave 4x4 of 16x16x32.
 * BK=64: per K-step 2 sub-k MFMA passes -> half the barrier/stall count.
 * LDS [128 rows][64 shorts=128B], double buffered: 64 KB total.
 * Bank-conflict fix (rule #21): linear LDS dest (global_load_lds),
 * XOR-permuted GLOBAL source seg, matching XOR on the ds_read slot.
 *   stage: lane i loads global(row = w*8 + r*32 + (i>>3),
 *                              seg = (i&7) ^ ((i>>3)&7))  -> lds + i*16B
 *   read : global(row, s) lives at LDS[row][s ^ (row&7)], row&7 == m16&7
 * => every 8-lane phase hits all 8 bank-quads once (conflict-free).
 * ===================================================================== */
__device__ __forceinline__ void mfma_core(const bf16* __restrict__ Ab, int lda,
                                          const bf16* __restrict__ Bb, int ldb,
                                          int nsteps /* K/64 */, short* As, short* Bs,
                                          f32x4 (&acc)[4][4]) {
    const int tid = threadIdx.x;
    const int lane = tid & 63;
    const int wave = tid >> 6;
    const int wy = wave >> 1, wx = wave & 1;
    const int m16 = lane & 15, quad = lane >> 4;
    const int sr = lane >> 3;                 /* row-in-8 for staging */
    const int sseg = (lane & 7) ^ sr;         /* swizzled source segment */
    const bf16* aP = Ab + (size_t)(wave * 8 + sr) * lda + sseg * 8;
    const bf16* bP = Bb + (size_t)(wave * 8 + sr) * ldb + sseg * 8;
    short* aL = As + wave * 512;              /* wave-uniform LDS dests */
    short* bL = Bs + wave * 512;
    /* prologue: stage K-tile 0 into buffer 0 (4 rounds x 32 rows each) */
    #pragma unroll
    for (int r = 0; r < 4; r++) {
        gload_lds16(aP + (size_t)(r * 32) * lda, aL + r * 2048);
        gload_lds16(bP + (size_t)(r * 32) * ldb, bL + r * 2048);
    }
    asm volatile("s_waitcnt vmcnt(0)" ::: "memory");
    __builtin_amdgcn_s_barrier();
    const int swz = m16 & 7;
    for (int ks = 0; ks < nsteps; ks++) {
        const int cur = (ks & 1) * 8192;      /* buffer offset in shorts */
        const int nxt = 8192 - cur;
        if (ks + 1 < nsteps) {                /* prefetch next K-tile */
            const int ko = (ks + 1) * 64;
            #pragma unroll
            for (int r = 0; r < 4; r++) {
                gload_lds16(aP + (size_t)(r * 32) * lda + ko, aL + nxt + r * 2048);
                gload_lds16(bP + (size_t)(r * 32) * ldb + ko, bL + nxt + r * 2048);
            }
        }
        #pragma unroll
        for (int kk = 0; kk < 2; kk++) {
            short8 af[4], bfv[4];
            #pragma unroll
            for (int i = 0; i < 4; i++)
                af[i] = *(const short8*)&As[cur + (wy * 64 + i * 16 + m16) * 64 +
                                            (((kk * 4 + quad) ^ swz) * 8)];
            #pragma unroll
            for (int j = 0; j < 4; j++)
                bfv[j] = *(const short8*)&Bs[cur + (wx * 64 + j * 16 + m16) * 64 +
                                             (((kk * 4 + quad) ^ swz) * 8)];
            #pragma unroll
            for (int i = 0; i < 4; i++)
                #pragma unroll
                for (int j = 0; j < 4; j++)
                    acc[i][j] = __builtin_amdgcn_mfma_f32_16x16x32_bf16(af[i], bfv[j], acc[i][j], 0, 0, 0);
        }
        asm volatile("s_waitcnt vmcnt(0)" ::: "memory");
        __builtin_amdgcn_s_barrier();
    }
}

/* ---- W (500x500 fp32 [k][n]) -> Wt (512x512 bf16 [n][k]) ---- */
__global__ void transpose_w3(const float* __restrict__ WK, const float* __restrict__ WQ,
                             const float* __restrict__ WV, bf16* __restrict__ Wt_all) {
    const float* W = (blockIdx.z == 0) ? WK : (blockIdx.z == 1) ? WQ : WV;
    bf16* Wt = Wt_all + (size_t)blockIdx.z * NDP * NDP;
    __shared__ float t[32][33];
    int n0 = blockIdx.x * 32, k0 = blockIdx.y * 32;
    int a = threadIdx.x & 31, bq = threadIdx.x >> 5;
    #pragma unroll
    for (int it = 0; it < 4; it++) {
        int k = k0 + bq + it * 8, n = n0 + a;
        t[bq + it * 8][a] = (k < ND && n < ND) ? W[k * ND + n] : 0.f;
    }
    __syncthreads();
    #pragma unroll
    for (int it = 0; it < 4; it++) {
        int n = n0 + bq + it * 8;
        Wt[(size_t)n * NDP + k0 + a] = __float2bfloat16(t[a][bq + it * 8]);
    }
}

/* ---- build g (B,T,512) bf16 ---- */
__global__ void build_g(const int* __restrict__ words, const int* __restrict__ pos,
                        const int* __restrict__ ner, const int* __restrict__ chunks,
                        const int* __restrict__ subj_pos, const int* __restrict__ obj_pos,
                        const int* __restrict__ on_path, const float* __restrict__ dep_feat,
                        const float* __restrict__ emb_w, const float* __restrict__ pos_w,
                        const float* __restrict__ ner_w, const float* __restrict__ chunk_w,
                        const float* __restrict__ position_w, bf16* __restrict__ g) {
    int tok = blockIdx.x;
    int w = words[tok], p = pos[tok], n = ner[tok], ck = chunks[tok];
    int sp = subj_pos[tok], op = obj_pos[tok], onp = on_path[tok];
    bf16* gr = g + (size_t)tok * NDP;
    for (int d = threadIdx.x; d < NDP; d += blockDim.x) {
        float v;
        if      (d < 300) v = emb_w[(size_t)w * 300 + d];
        else if (d < 335) v = pos_w[p * 35 + (d - 300)];
        else if (d < 365) v = ner_w[n * 30 + (d - 335)];
        else if (d < 395) v = chunk_w[ck * 30 + (d - 365)];
        else if (d < 425) v = position_w[sp * 30 + (d - 395)];
        else if (d < 455) v = position_w[op * 30 + (d - 425)];
        else if (d == 455) v = (float)onp;
        else if (d < 500) v = dep_feat[(size_t)tok * 44 + (d - 456)];
        else              v = 0.f;
        gr[d] = __float2bfloat16(v);
    }
}

/* ---- subj max pool partials ---- */
__global__ void pool_part(const bf16* __restrict__ g, const int* __restrict__ subj_pos,
                          float* __restrict__ part) {
    int b = blockIdx.x, s = blockIdx.y;
    int c0 = threadIdx.x * 8;
    const bf16* gb = g + (size_t)b * NT * NDP + c0;
    const int* sp = subj_pos + b * NT;
    float mx[8];
    #pragma unroll
    for (int i = 0; i < 8; i++) mx[i] = -INFINITY;
    int t0 = s * (NT / TSP), t1 = t0 + (NT / TSP);
    for (int t = t0; t < t1; t++) {
        int masked = (sp[t] != 0);
        short8 v8 = *(const short8*)(gb + (size_t)t * NDP);
        #pragma unroll
        for (int i = 0; i < 8; i++) {
            float v = masked ? -1e12f : b2f(((bf16*)&v8)[i]);
            mx[i] = fmaxf(mx[i], v);
        }
    }
    float* pr = part + ((size_t)(b * TSP + s)) * NDP + c0;
    #pragma unroll
    for (int i = 0; i < 8; i++) pr[i] = mx[i];
}

/* =====================================================================
 * Parallel fused GEMVs: grid (NB, 4 d-chunks) x 512 thr.
 * ===================================================================== */

/* pool-reduce -> subj; q = relu(subj @ (Wq0+Wq1) + bq) */
__global__ __launch_bounds__(512) void gemv_q(const float* __restrict__ part,
                                              const float* __restrict__ Wq_w, const float* __restrict__ Wq_b,
                                              float* __restrict__ subj, float* __restrict__ qb) {
    int b = blockIdx.x, dch = blockIdx.y, tid = threadIdx.x;
    __shared__ float xs[512];
    __shared__ float red[512];
    float mx = -INFINITY;
    #pragma unroll
    for (int s = 0; s < TSP; s++) mx = fmaxf(mx, part[((size_t)(b * TSP + s)) * NDP + tid]);
    xs[tid] = (tid < ND) ? mx : 0.f;
    if (dch == 0 && tid < ND) subj[b * ND + tid] = mx;
    __syncthreads();
    int jg = tid >> 7, dl = tid & 127, d = dch * 128 + dl;
    float acc = 0.f;
    if (d < ND) {
        int j0 = jg * 125;
        const float* w0 = Wq_w + (size_t)j0 * ND + d;
        const float* w1 = w0 + (size_t)ND * ND;
        #pragma unroll 5
        for (int j = 0; j < 125; j++)
            acc += xs[j0 + j] * (w0[(size_t)j * ND] + w1[(size_t)j * ND]);
    }
    red[tid] = acc;
    __syncthreads();
    if (jg == 0 && d < ND) {
        float s = (red[dl] + red[128 + dl]) + (red[256 + dl] + red[384 + dl]);
        qb[b * ND + d] = fmaxf(s + Wq_b[d], 0.f);
    }
}

/* w2 = relu(q @ Wc0 + bc) * Wk */
__global__ __launch_bounds__(512) void gemv_w2(const float* __restrict__ qb,
                                               const float* __restrict__ Wc_w, const float* __restrict__ Wc_b,
                                               const float* __restrict__ Wk_w, float* __restrict__ w2) {
    int b = blockIdx.x, dch = blockIdx.y, tid = threadIdx.x;
    __shared__ float xs[512];
    __shared__ float red[512];
    xs[tid] = (tid < ND) ? qb[b * ND + tid] : 0.f;
    __syncthreads();
    int jg = tid >> 7, dl = tid & 127, d = dch * 128 + dl;
    float acc = 0.f;
    if (d < ND) {
        int j0 = jg * 125;
        const float* w0 = Wc_w + (size_t)j0 * ND + d;
        #pragma unroll 5
        for (int j = 0; j < 125; j++)
            acc += xs[j0 + j] * w0[(size_t)j * ND];
    }
    red[tid] = acc;
    __syncthreads();
    if (jg == 0 && d < ND) {
        float s = (red[dl] + red[128 + dl]) + (red[256 + dl] + red[384 + dl]);
        w2[b * ND + d] = fmaxf(s + Wc_b[d], 0.f) * Wk_w[d];
    }
}

/* c-reduce; m = relu(c @ Wm0 + subj @ (Wm1+Wm2) + bm) */
__global__ __launch_bounds__(512) void gemv_m(const float* __restrict__ part,
                                              const float* __restrict__ subj,
                                              const float* __restrict__ Wm_w, const float* __restrict__ Wm_b,
                                              float* __restrict__ mv) {
    int b = blockIdx.x, dch = blockIdx.y, tid = threadIdx.x;
    __shared__ float cs[512];
    __shared__ float ss[512];
    __shared__ float red[512];
    float a = 0.f;
    #pragma unroll
    for (int s = 0; s < TSP; s++) a += part[((size_t)(b * TSP + s)) * NDP + tid];
    cs[tid] = (tid < ND) ? a : 0.f;
    ss[tid] = (tid < ND) ? subj[b * ND + tid] : 0.f;
    __syncthreads();
    int jg = tid >> 7, dl = tid & 127, d = dch * 128 + dl;
    float acc = 0.f;
    if (d < ND) {
        int j0 = jg * 125;
        const float* w0 = Wm_w + (size_t)j0 * ND + d;
        const float* w1 = w0 + (size_t)ND * ND;
        const float* w2p = w0 + (size_t)2 * ND * ND;
        #pragma unroll 5
        for (int j = 0; j < 125; j++) {
            acc += cs[j0 + j] * w0[(size_t)j * ND];
            acc += ss[j0 + j] * (w1[(size_t)j * ND] + w2p[(size_t)j * ND]);
        }
    }
    red[tid] = acc;
    __syncthreads();
    if (jg == 0 && d < ND) {
        float s = (red[dl] + red[128 + dl]) + (red[256 + dl] + red[384 + dl]);
        mv[b * ND + d] = fmaxf(s + Wm_b[d], 0.f);
    }
}

/* ---- klog ---- */
__global__ void compute_klog(const bf16* __restrict__ g, const float* __restrict__ w2,
                             const float* __restrict__ Wk_b, float* __restrict__ klog) {
    int tok = blockIdx.x * 4 + (threadIdx.x >> 6);
    int lane = threadIdx.x & 63;
    int b = tok >> 10;
    const bf16* gr = g + (size_t)tok * NDP + lane * 8;
    const float* wr = w2 + b * ND + lane * 8;
    short8 v8 = *(const short8*)gr;
    float acc = 0.f;
    #pragma unroll
    for (int i = 0; i < 8; i++) acc += b2f(((bf16*)&v8)[i]) * wr[i];
    #pragma unroll
    for (int off = 32; off; off >>= 1) acc += __shfl_down(acc, off, 64);
    if (lane == 0) klog[tok] = acc + Wk_b[0];
}

/* ---- softmax over T ---- */
__global__ void softmax_k(const float* __restrict__ klog, float* __restrict__ k) {
    int b = blockIdx.x, tid = threadIdx.x;
    __shared__ float red[256];
    float m = -INFINITY;
    for (int t = tid; t < NT; t += 256) m = fmaxf(m, klog[b * NT + t]);
    red[tid] = m; __syncthreads();
    for (int s = 128; s; s >>= 1) { if (tid < s) red[tid] = fmaxf(red[tid], red[tid + s]); __syncthreads(); }
    m = red[0]; __syncthreads();
    float sum = 0.f;
    for (int t = tid; t < NT; t += 256) sum += expf(klog[b * NT + t] - m);
    red[tid] = sum; __syncthreads();
    for (int s = 128; s; s >>= 1) { if (tid < s) red[tid] += red[tid + s]; __syncthreads(); }
    float inv = 1.f / red[0];
    for (int t = tid; t < NT; t += 256) k[b * NT + t] = expf(klog[b * NT + t] - m) * inv;
}

/* ---- c = sum_t k*g partials ---- */
__global__ void c_part(const bf16* __restrict__ g, const float* __restrict__ k,
                       float* __restrict__ part) {
    int b = blockIdx.x, s = blockIdx.y;
    int c0 = threadIdx.x * 8;
    const bf16* gb = g + (size_t)b * NT * NDP + c0;
    const float* kb = k + b * NT;
    float acc[8] = {};
    int t0 = s * (NT / TSP), t1 = t0 + (NT / TSP);
    for (int t = t0; t < t1; t++) {
        float kv = kb[t];
        short8 v8 = *(const short8*)(gb + (size_t)t * NDP);
        #pragma unroll
        for (int i = 0; i < 8; i++) acc[i] += kv * b2f(((bf16*)&v8)[i]);
    }
    float* pr = part + ((size_t)(b * TSP + s)) * NDP + c0;
    #pragma unroll
    for (int i = 0; i < 8; i++) pr[i] = acc[i];
}

/* ---- MFMA projections K/Q/V, natural grid (bx innermost: g-panel sharers
 *      land on the same XCD -> L2 reuse).  z==2 writes transposed Vt. ---- */
__global__ __launch_bounds__(256) void mfma_proj3(const bf16* __restrict__ g, const bf16* __restrict__ Wt_all,
                                                  const float* __restrict__ bK, const float* __restrict__ bQ,
                                                  const float* __restrict__ bV, bf16* __restrict__ kqv,
                                                  bf16* __restrict__ valT) {
    __shared__ short LB[32768];           /* 64 KB */
    short* As = LB;
    short* Bs = LB + 16384;
    f32x4 acc[4][4] = {};
    const int zz = blockIdx.z;
    const bf16* Wt = Wt_all + (size_t)zz * NDP * NDP;
    const float* bias = (zz == 0) ? bK : (zz == 1) ? bQ : bV;
    bf16* out = kqv + (size_t)zz * NTOK * NDP;
    int row0 = blockIdx.x * 128, col0 = blockIdx.y * 128;
    mfma_core(g + (size_t)row0 * NDP, NDP, Wt + (size_t)col0 * NDP, NDP, NDP / 64, As, Bs, acc);
    const int tid = threadIdx.x, lane = tid & 63, wave = tid >> 6;
    const int wx = wave & 1, wy = wave >> 1, m16 = lane & 15, quad = lane >> 4;
    bf16* Ct = (bf16*)LB;                 /* 64 x 128 bf16 half-tile */
    int rl = tid >> 4, cs = (tid & 15) * 8;
    int bI = row0 >> 10, sBase = row0 & 1023;
    #pragma unroll
    for (int h = 0; h < 2; h++) {
        if (wy == h) {
            #pragma unroll
            for (int j = 0; j < 4; j++) {
                int cl = wx * 64 + j * 16 + m16;
                int cg = col0 + cl;
                float bv = (cg < ND) ? bias[cg] : 0.f;
                bool ok = (cg < ND);
                #pragma unroll
                for (int i = 0; i < 4; i++)
                    #pragma unroll
                    for (int reg = 0; reg < 4; reg++)
                        Ct[(i * 16 + quad * 4 + reg) * 128 + cl] =
                            __float2bfloat16(ok ? (acc[i][j][reg] + bv) : 0.f);
            }
        }
        __syncthreads();
        if (zz < 2) {
            #pragma unroll
            for (int p = 0; p < 4; p++) {
                int row_l = p * 16 + rl;
                *(short8*)(out + (size_t)(row0 + h * 64 + row_l) * NDP + col0 + cs) =
                    *(const short8*)&Ct[row_l * 128 + cs];
            }
        } else {
            /* transposed store: valT[(b*NDP + c)*NT + s] */
            int cl2 = tid & 127, sh = tid >> 7;
            bf16* dst = valT + ((size_t)(bI * NDP + col0 + cl2)) * NT + sBase + h * 64 + sh * 32;
            #pragma unroll
            for (int kk = 0; kk < 8; kk++) {
                short4v o;
                #pragma unroll
                for (int e = 0; e < 4; e++)
                    ((bf16*)&o)[e] = Ct[(sh * 32 + kk * 4 + e) * 128 + cl2];
                *(short4v*)(dst + kk * 4) = o;
            }
        }
        __syncthreads();
    }
}

/* ---- MFMA S: 1-D grid, each XCD owns whole z-batches (key+query = 2MB < 4MB L2) ---- */
__global__ __launch_bounds__(256) void mfma_S(const bf16* __restrict__ key, const bf16* __restrict__ query,
                                              bf16* __restrict__ S) {
    __shared__ short LB[32768];
    short* As = LB;
    short* Bs = LB + 16384;
    f32x4 acc[4][4] = {};
    /* lin = xcd + 8*(i + 64*zh); z = xcd + 8*zh; i = bx + 8*by */
    int lin = blockIdx.x;
    int xcd = lin & 7, j = lin >> 3;
    int i = j & 63, z = xcd + 8 * (j >> 6);
    int bx = i & 7, by = i >> 3;
    int row0 = bx * 128, col0 = by * 128;
    const bf16* kb = key + (size_t)z * NT * NDP;
    const bf16* qb = query + (size_t)z * NT * NDP;
    mfma_core(kb + (size_t)row0 * NDP, NDP, qb + (size_t)col0 * NDP, NDP, NDP / 64, As, Bs, acc);
    bf16* Sb = S + ((size_t)z << 20);
    const int tid = threadIdx.x, lane = tid & 63, wave = tid >> 6;
    const int wx = wave & 1, wy = wave >> 1, m16 = lane & 15, quad = lane >> 4;
    bf16* Ct = (bf16*)LB;
    int rl = tid >> 4, cs = (tid & 15) * 8;
    #pragma unroll
    for (int h = 0; h < 2; h++) {
        if (wy == h) {
            #pragma unroll
            for (int j2 = 0; j2 < 4; j2++) {
                int cl = wx * 64 + j2 * 16 + m16;
                #pragma unroll
                for (int i2 = 0; i2 < 4; i2++)
                    #pragma unroll
                    for (int reg = 0; reg < 4; reg++)
                        Ct[(i2 * 16 + quad * 4 + reg) * 128 + cl] = __float2bfloat16(acc[i2][j2][reg]);
            }
        }
        __syncthreads();
        #pragma unroll
        for (int p = 0; p < 4; p++) {
            int row_l = p * 16 + rl;
            *(short8*)(Sb + (((size_t)(row0 + h * 64 + row_l)) << 10) + col0 + cs) =
                *(const short8*)&Ct[row_l * 128 + cs];
        }
        __syncthreads();
    }
}

/* ---- double softmax: one wave per row, in-place P2; z-XCD affinity ---- */
__global__ __launch_bounds__(256) void attn_rows(bf16* __restrict__ S, float* __restrict__ att_out) {
    /* lin = xcd + 8*(i + 256*zh); z = xcd + 8*zh (matches mfma_S / mfma_PV) */
    int lin = blockIdx.x;
    int xcd = lin & 7, t2 = lin >> 3;
    int i2 = t2 & 255, zh = t2 >> 8;
    int z = xcd + 8 * zh;
    int gr = z * 1024 + i2 * 4 + (threadIdx.x >> 6);
    int t = gr & 1023;
    int lane = threadIdx.x & 63;
    bf16* row = S + ((size_t)gr << 10) + lane * 16;
    short8 r0 = *(const short8*)row;
    short8 r1 = *(const short8*)(row + 8);
    float v[16];
    #pragma unroll
    for (int i = 0; i < 8; i++) { v[i] = b2f(((bf16*)&r0)[i]); v[8 + i] = b2f(((bf16*)&r1)[i]); }
    float m = -INFINITY;
    #pragma unroll
    for (int i = 0; i < 16; i++) m = fmaxf(m, v[i]);
    #pragma unroll
    for (int off = 32; off; off >>= 1) m = fmaxf(m, __shfl_xor(m, off, 64));
    float s1 = 0.f, s2 = 0.f, dg = 0.f;
    int tloc = t - lane * 16;
    #pragma unroll
    for (int i = 0; i < 16; i++) {
        float e1 = expf(v[i] - m);
        float e2 = expf((v[i] - m) * INV_SCALE);
        s1 += e1; s2 += e2;
        if (i == tloc) dg = e1;
        v[i] = e2;
    }
    #pragma unroll
    for (int off = 32; off; off >>= 1) {
        s1 += __shfl_xor(s1, off, 64);
        s2 += __shfl_xor(s2, off, 64);
        dg += __shfl_xor(dg, off, 64);
    }
    if (lane == 0) att_out[gr] = (1.f - dg / s1) * INV_SCALE;
    float inv2 = 1.f / s2;
    #pragma unroll
    for (int i = 0; i < 8; i++) {
        ((bf16*)&r0)[i] = __float2bfloat16(v[i] * inv2);
        ((bf16*)&r1)[i] = __float2bfloat16(v[8 + i] * inv2);
    }
    *(short8*)row = r0;
    *(short8*)(row + 8) = r1;
}

/* ---- MFMA PV: 1-D grid, each XCD owns whole z-batches (P2 2MB + Vt 1MB < 4MB L2) ---- */
__global__ __launch_bounds__(256) void mfma_PV(const bf16* __restrict__ S, const bf16* __restrict__ valueT,
                                               const float* __restrict__ mvec, float* __restrict__ outp) {
    __shared__ short LB[32768];
    short* As = LB;
    short* Bs = LB + 16384;
    f32x4 acc[4][4] = {};
    /* lin = xcd + 8*(i + 32*zh); z = xcd + 8*zh; i = bx + 8*by */
    int lin = blockIdx.x;
    int xcd = lin & 7, j = lin >> 3;
    int i = j & 31, z = xcd + 8 * (j >> 5);
    int bx = i & 7, by = i >> 3;
    int row0 = bx * 128, col0 = by * 128;
    const bf16* P2 = S + ((size_t)z << 20);
    const bf16* Vt = valueT + (size_t)z * NDP * NT;
    mfma_core(P2 + (size_t)row0 * NT, NT, Vt + (size_t)col0 * NT, NT, NT / 64, As, Bs, acc);
    const int tid = threadIdx.x, lane = tid & 63, wave = tid >> 6;
    const int wx = wave & 1, wy = wave >> 1, m16 = lane & 15, quad = lane >> 4;
    float* Ct = (float*)LB;               /* 64 x 128 fp32 half-tile = 32 KB */
    int rl = tid >> 4, cs = (tid & 15) * 8;
    #pragma unroll
    for (int h = 0; h < 2; h++) {
        if (wy == h) {
            #pragma unroll
            for (int j2 = 0; j2 < 4; j2++) {
                int cl = wx * 64 + j2 * 16 + m16;
                int cg = col0 + cl;
                float mm = (cg < ND) ? mvec[z * ND + cg] : 0.f;
                #pragma unroll
                for (int i2 = 0; i2 < 4; i2++)
                    #pragma unroll
                    for (int reg = 0; reg < 4; reg++)
                        Ct[(i2 * 16 + quad * 4 + reg) * 128 + cl] = acc[i2][j2][reg] * mm;
            }
        }
        __syncthreads();
        #pragma unroll
        for (int p = 0; p < 4; p++) {
            int row_l = p * 16 + rl;
            int r = row0 + h * 64 + row_l;
            float* orow = outp + (size_t)(z * NT + r) * ND + col0 + cs;
            const float* src = &Ct[row_l * 128 + cs];
            if (col0 + cs + 8 <= ND) {
                *(f32x4*)orow = *(const f32x4*)src;
                *(f32x4*)(orow + 4) = *(const f32x4*)(src + 4);
            } else {
                #pragma unroll
                for (int e = 0; e < 8; e++)
                    if (col0 + cs + e < ND) orow[e] = src[e];
            }
        }
        __syncthreads();
    }
}

extern "C" void kernel_launch(void* const* d_in, const int* in_sizes, int n_in,
                              void* d_out, int out_size, void* d_ws, size_t ws_size,
                              hipStream_t stream) {
    const int*   words     = (const int*)d_in[0];
    const int*   pos       = (const int*)d_in[2];
    const int*   ner       = (const int*)d_in[3];
    const int*   subj_pos  = (const int*)d_in[4];
    const int*   obj_pos   = (const int*)d_in[5];
    const int*   chunks    = (const int*)d_in[6];
    const int*   on_path   = (const int*)d_in[7];
    const float* dep_feat  = (const float*)d_in[8];
    const float* emb_w     = (const float*)d_in[9];
    const float* pos_w     = (const float*)d_in[10];
    const float* ner_w     = (const float*)d_in[11];
    const float* chunk_w   = (const float*)d_in[12];
    const float* position_w= (const float*)d_in[13];
    const float* Wq_w      = (const float*)d_in[14];
    const float* Wq_b      = (const float*)d_in[15];
    const float* Wc_w      = (const float*)d_in[16];
    const float* Wc_b      = (const float*)d_in[17];
    const float* Wk_w      = (const float*)d_in[18];
    const float* Wk_b      = (const float*)d_in[19];
    const float* Wm_w      = (const float*)d_in[20];
    const float* Wm_b      = (const float*)d_in[21];
    const float* K_w       = (const float*)d_in[22];
    const float* K_b       = (const float*)d_in[23];
    const float* Q_w       = (const float*)d_in[24];
    const float* Q_b       = (const float*)d_in[25];
    const float* V_w       = (const float*)d_in[26];
    const float* V_b       = (const float*)d_in[27];

    float* out_main = (float*)d_out;
    float* out_att  = out_main + (size_t)NTOK * ND;

    /* ---- ws layout (~116 MB, unchanged) ---- */
    char* wp = (char*)d_ws;
    float* subj = (float*)wp; wp += (size_t)NB * ND * 4;
    float* qb   = (float*)wp; wp += (size_t)NB * ND * 4;
    float* w2   = (float*)wp; wp += (size_t)NB * ND * 4;
    float* cb   = (float*)wp; wp += (size_t)NB * ND * 4;   /* unused (kept for layout) */
    float* mv   = (float*)wp; wp += (size_t)NB * ND * 4;
    float* klog = (float*)wp; wp += (size_t)NB * NT * 4;
    float* kbuf = (float*)wp; wp += (size_t)NB * NT * 4;
    float* part = (float*)wp; wp += (size_t)NB * TSP * NDP * 4;
    bf16* g     = (bf16*)wp;  wp += (size_t)NTOK * NDP * 2;
    bf16* Wt    = (bf16*)wp;  wp += (size_t)3 * NDP * NDP * 2;
    bf16* kqv   = (bf16*)wp;  wp += (size_t)3 * NTOK * NDP * 2;  /* key | query | (value region unused) */
    bf16* valT  = (bf16*)wp;  wp += (size_t)NTOK * NDP * 2;      /* Vt[b][c][s] */
    bf16* S     = (bf16*)wp;                                     /* NB<<20 bf16 = 32 MB */

    bf16* key   = kqv;
    bf16* query = kqv + (size_t)NTOK * NDP;
    (void)cb;

    transpose_w3<<<dim3(16, 16, 3), 256, 0, stream>>>(K_w, Q_w, V_w, Wt);

    /* phase A */
    build_g<<<NTOK, 128, 0, stream>>>(words, pos, ner, chunks, subj_pos, obj_pos,
                                      on_path, dep_feat, emb_w, pos_w, ner_w,
                                      chunk_w, position_w, g);
    pool_part<<<dim3(NB, TSP), 64, 0, stream>>>(g, subj_pos, part);
    gemv_q<<<dim3(NB, 4), 512, 0, stream>>>(part, Wq_w, Wq_b, subj, qb);
    gemv_w2<<<dim3(NB, 4), 512, 0, stream>>>(qb, Wc_w, Wc_b, Wk_w, w2);
    compute_klog<<<NTOK / 4, 256, 0, stream>>>(g, w2, Wk_b, klog);
    softmax_k<<<NB, 256, 0, stream>>>(klog, kbuf);
    c_part<<<dim3(NB, TSP), 64, 0, stream>>>(g, kbuf, part);
    gemv_m<<<dim3(NB, 4), 512, 0, stream>>>(part, subj, Wm_w, Wm_b, mv);

    /* phase B */
    mfma_proj3<<<dim3(NTOK / 128, NDP / 128, 3), 256, 0, stream>>>(g, Wt, K_b, Q_b, V_b, kqv, valT);
    mfma_S<<<1024, 256, 0, stream>>>(key, query, S);
    attn_rows<<<NTOK / 4, 256, 0, stream>>>(S, out_att);
    mfma_PV<<<512, 256, 0, stream>>>(S, valT, mv, out_main);

    (void)in_sizes; (void)n_in; (void)out_size; (void)ws_size;
}